// Round 1
// 1337.849 us; speedup vs baseline: 5.6698x; 5.6698x over previous
//
#include <hip/hip_runtime.h>
#include <cstdint>
#include <cstddef>

typedef unsigned short u16;

#define L_TOK 16384
#define DMODEL 256
#define NHEAD 8
#define HDIM 32

typedef __attribute__((ext_vector_type(8))) short bf16x8;
typedef __attribute__((ext_vector_type(4))) float f32x4;

__device__ __forceinline__ float bf2f(u16 u) {
    union { unsigned int i; float f; } v; v.i = ((unsigned int)u) << 16; return v.f;
}
__device__ __forceinline__ u16 f2bf(float f) {
    union { unsigned int i; float f; } v; v.f = f;
    unsigned int i = v.i;
    unsigned int r = (i + 0x7FFFu + ((i >> 16) & 1u)) >> 16;
    return (u16)r;
}

// ---------------- sentinel fill (FLOAT output) ----------------
__global__ __launch_bounds__(256) void fill_kernel(float* __restrict__ out, int n, float v) {
    int t = blockIdx.x * 256 + threadIdx.x;
    if (t < n) out[t] = v;
}

// x[l*256+d] = src[d*16384+l]  (src is (C, H*W) f32, natural layout)
__global__ __launch_bounds__(256) void xpose_kernel(const float* __restrict__ in,
                                                    u16* __restrict__ out) {
    int idx = blockIdx.x * 256 + threadIdx.x;
    if (idx >= L_TOK * DMODEL) return;
    int d = idx / L_TOK, l = idx - d * L_TOK;
    out[(size_t)l * DMODEL + d] = f2bf(in[idx]);
}

// q = x + pos^T
__global__ __launch_bounds__(256) void addq_kernel(const u16* __restrict__ x,
                                                   const float* __restrict__ p,
                                                   u16* __restrict__ q) {
    int idx = blockIdx.x * 256 + threadIdx.x;
    int l = idx >> 8, d = idx & 255;
    q[idx] = f2bf(bf2f(x[idx]) + p[(size_t)d * L_TOK + l]);
}

// ---------------- weight prepack: f32 [K][N] -> bf16 hi/lo transposed [Npad][K] ----
__global__ __launch_bounds__(256) void prepack_kernel(const float* __restrict__ W,
                                                      u16* __restrict__ hi,
                                                      u16* __restrict__ lo,
                                                      int K, int N, int Npad) {
    int idx = blockIdx.x * 256 + threadIdx.x;
    if (idx >= Npad * K) return;
    int n = idx / K, k = idx - n * K;
    float w = (n < N) ? W[(size_t)k * N + n] : 0.f;
    u16 h = f2bf(w);
    float rem = w - bf2f(h);
    hi[idx] = h;
    lo[idx] = f2bf(rem);
}

// ---------------- MFMA GEMM ----------------
// C[M][ldC](bf16) = A[M][K](bf16) @ (Whi+Wlo)^T  + bias, optional relu.
// Whi/Wlo are [Npad][K] (n-major). Tile: BM=128 x BN=64, BK=64, 4 waves.
// grid: (Npad/64, M/128)
#define BM 128
#define BN 64
#define BK 64

__global__ __launch_bounds__(256) void gemm_mfma(const u16* __restrict__ A,
                                                 const u16* __restrict__ Bhi,
                                                 const u16* __restrict__ Blo,
                                                 const float* __restrict__ bias,
                                                 u16* __restrict__ C,
                                                 int K, int Nact, int ldC, int relu) {
    __shared__ u16 lA[BM][BK + 8];
    __shared__ u16 lBh[BN][BK + 8];
    __shared__ u16 lBl[BN][BK + 8];

    const int tid  = threadIdx.x;
    const int lane = tid & 63;
    const int wave = tid >> 6;
    const int wm   = wave >> 1;   // 0..1, which 64-row half
    const int wn   = wave & 1;    // 0..1, which 32-col half
    const int row  = lane & 15;
    const int kch  = lane >> 4;   // 0..3

    const int m0 = blockIdx.y * BM;
    const int n0 = blockIdx.x * BN;

    f32x4 acc[4][2] = {};

    const int nkt = K / BK;
    for (int kt = 0; kt < nkt; ++kt) {
        const int kb0 = kt * BK;
        // stage A: 128x64, 16B per thread x 4
#pragma unroll
        for (int it = 0; it < 4; ++it) {
            int li = it * 256 + tid;
            int r = li >> 3, c8 = li & 7;
            bf16x8 v = *(const bf16x8*)(A + (size_t)(m0 + r) * K + kb0 + c8 * 8);
            *(bf16x8*)(&lA[r][c8 * 8]) = v;
        }
        // stage Bhi/Blo: 64x64 each
#pragma unroll
        for (int it = 0; it < 2; ++it) {
            int li = it * 256 + tid;
            int r = li >> 3, c8 = li & 7;
            bf16x8 vh = *(const bf16x8*)(Bhi + (size_t)(n0 + r) * K + kb0 + c8 * 8);
            bf16x8 vl = *(const bf16x8*)(Blo + (size_t)(n0 + r) * K + kb0 + c8 * 8);
            *(bf16x8*)(&lBh[r][c8 * 8]) = vh;
            *(bf16x8*)(&lBl[r][c8 * 8]) = vl;
        }
        __syncthreads();

#pragma unroll
        for (int kk = 0; kk < 2; ++kk) {
            const int kb = kk * 32 + kch * 8;
            bf16x8 af[4];
#pragma unroll
            for (int i = 0; i < 4; ++i)
                af[i] = *(const bf16x8*)(&lA[wm * 64 + i * 16 + row][kb]);
#pragma unroll
            for (int j = 0; j < 2; ++j) {
                bf16x8 bh = *(const bf16x8*)(&lBh[wn * 32 + j * 16 + row][kb]);
                bf16x8 bl = *(const bf16x8*)(&lBl[wn * 32 + j * 16 + row][kb]);
#pragma unroll
                for (int i = 0; i < 4; ++i) {
                    acc[i][j] = __builtin_amdgcn_mfma_f32_16x16x32_bf16(af[i], bh, acc[i][j], 0, 0, 0);
                    acc[i][j] = __builtin_amdgcn_mfma_f32_16x16x32_bf16(af[i], bl, acc[i][j], 0, 0, 0);
                }
            }
        }
        __syncthreads();
    }

    // epilogue: C/D layout col = lane&15, row = (lane>>4)*4 + reg
    const int cm0 = m0 + wm * 64 + (lane >> 4) * 4;
    const int cn0 = n0 + wn * 32 + (lane & 15);
#pragma unroll
    for (int j = 0; j < 2; ++j) {
        int cn = cn0 + j * 16;
        if (cn >= Nact) continue;
        float bv_ = bias[cn];
#pragma unroll
        for (int i = 0; i < 4; ++i) {
#pragma unroll
            for (int r = 0; r < 4; ++r) {
                float v = acc[i][j][r] + bv_;
                if (relu) v = fmaxf(v, 0.f);
                C[(size_t)(cm0 + i * 16 + r) * ldC + cn] = f2bf(v);
            }
        }
    }
}

__global__ __launch_bounds__(256) void softmax_kernel(u16* __restrict__ aw, int total) {
    int t = blockIdx.x * blockDim.x + threadIdx.x;
    if (t >= total) return;
    u16* pp = aw + (size_t)t * 25;
    float v[25];
    float mx = -1e30f;
    for (int k = 0; k < 25; k++) { v[k] = bf2f(pp[k]); mx = fmaxf(mx, v[k]); }
    float s = 0.f;
    for (int k = 0; k < 25; k++) { v[k] = __expf(v[k] - mx); s += v[k]; }
    float inv = 1.f / s;
    for (int k = 0; k < 25; k++) pp[k] = f2bf(v[k] * inv);
}

__global__ __launch_bounds__(256) void sample_kernel(const u16* __restrict__ val,
                                                     const u16* __restrict__ aw,
                                                     const u16* __restrict__ off,
                                                     u16* __restrict__ out) {
    int tid = blockIdx.x * blockDim.x + threadIdx.x;
    int hd = tid & 31;
    int pair = tid >> 5;          // l*NH + n
    int n = pair & 7;
    int l = pair >> 3;
    int iy = l >> 7, ix = l & 127;
    float cx = (ix + 0.5f) * (1.f / 128.f);
    float cy = (iy + 0.5f) * (1.f / 128.f);
    const u16* o = off + (size_t)pair * 4;
    float bx = cx + bf2f(o[0]) * (0.025f / 8.f);
    float by = cy + bf2f(o[1]) * (0.025f / 8.f);
    float bw = 0.025f + bf2f(o[2]) * (0.025f / 8.f);
    float bh = 0.025f + bf2f(o[3]) * (0.025f / 8.f);
    const u16* awp = aw + (size_t)pair * 25;
    float acc = 0.f;
    for (int k = 0; k < 25; k++) {
        float gx = (float)(k % 5 - 2) * 0.25f;
        float gy = (float)(k / 5 - 2) * 0.25f;
        float xx = (bx + bw * gx) * 128.f - 0.5f;
        float yy = (by + bh * gy) * 128.f - 0.5f;
        float x0 = floorf(xx), y0 = floorf(yy);
        float a_ = bf2f(awp[k]);
        for (int dy = 0; dy < 2; dy++) {
            for (int dx = 0; dx < 2; dx++) {
                float xi = x0 + dx, yi = y0 + dy;
                if (xi >= 0.f && xi < 128.f && yi >= 0.f && yi < 128.f) {
                    float w_ = (1.f - fabsf(xx - xi)) * (1.f - fabsf(yy - yi));
                    int idx = (int)yi * 128 + (int)xi;
                    acc += a_ * w_ * bf2f(val[(size_t)idx * 256 + n * 32 + hd]);
                }
            }
        }
    }
    out[(size_t)l * 256 + n * 32 + hd] = f2bf(acc);
}

// LN writing bf16 (intermediate layers)
__global__ __launch_bounds__(256) void ln_naive(const u16* __restrict__ xin,
                                                const u16* __restrict__ delta,
                                                const float* __restrict__ g,
                                                const float* __restrict__ b,
                                                u16* __restrict__ out) {
    int row = blockIdx.x * 256 + threadIdx.x;
    if (row >= L_TOK) return;
    size_t base = (size_t)row * 256;
    float sum = 0.f, sq = 0.f;
    for (int d = 0; d < 256; d++) {
        float v = bf2f(xin[base + d]) + bf2f(delta[base + d]);
        sum += v; sq += v * v;
    }
    float m = sum * (1.f / 256.f);
    float var = sq * (1.f / 256.f) - m * m;
    float r = rsqrtf(var + 1e-5f);
    for (int d = 0; d < 256; d++) {
        float v = bf2f(xin[base + d]) + bf2f(delta[base + d]);
        out[base + d] = f2bf((v - m) * r * g[d] + b[d]);
    }
}

// final LN writes FLOAT32 — d_out is the reference's output dtype (f32)
__global__ __launch_bounds__(256) void ln_final_f32(const u16* __restrict__ xin,
                                                    const u16* __restrict__ delta,
                                                    const float* __restrict__ g,
                                                    const float* __restrict__ b,
                                                    float* __restrict__ out) {
    int row = blockIdx.x * 256 + threadIdx.x;
    if (row >= L_TOK) return;
    size_t base = (size_t)row * 256;
    float sum = 0.f, sq = 0.f;
    for (int d = 0; d < 256; d++) {
        float v = bf2f(xin[base + d]) + bf2f(delta[base + d]);
        sum += v; sq += v * v;
    }
    float m = sum * (1.f / 256.f);
    float var = sq * (1.f / 256.f) - m * m;
    float r = rsqrtf(var + 1e-5f);
    for (int d = 0; d < 256; d++) {
        float v = bf2f(xin[base + d]) + bf2f(delta[base + d]);
        out[base + d] = (v - m) * r * g[d] + b[d];
    }
}

extern "C" void kernel_launch(void* const* d_in, const int* in_sizes, int n_in,
                              void* d_out, int out_size, void* d_ws, size_t ws_size,
                              hipStream_t stream) {
    const size_t MiB = 1048576;
    float* outp = (float*)d_out;
    int fillg = (out_size + 255) / 256;

    // ---- environment sentinels ----
    const int exp_sizes[18] = {4194304, 4194304, 131072, 512, 16384, 64, 102400, 400,
                               131072, 512, 524288, 2048, 524288, 512, 512, 512, 512, 512};
    bool env_ok = (n_in == 18) && (ws_size >= 25 * MiB) && (out_size == 4194304);
    if (env_ok) for (int i = 0; i < 18; i++) env_ok = env_ok && (in_sizes[i] == exp_sizes[i]);
    if (!env_ok) {
        hipLaunchKernelGGL(fill_kernel, dim3(fillg), dim3(256), 0, stream, outp, out_size, 3000.f);
        return;
    }

    const float* srcp  = (const float*)d_in[0];
    const float* posp  = (const float*)d_in[1];
    const float* Wv    = (const float*)d_in[2];
    const float* bv    = (const float*)d_in[3];
    const float* Wbox  = (const float*)d_in[4];
    const float* bbox  = (const float*)d_in[5];
    const float* Wattn = (const float*)d_in[6];
    const float* battn = (const float*)d_in[7];
    const float* Wo    = (const float*)d_in[8];
    const float* bo    = (const float*)d_in[9];
    const float* W1    = (const float*)d_in[10];
    const float* b1    = (const float*)d_in[11];
    const float* W2    = (const float*)d_in[12];
    const float* b2    = (const float*)d_in[13];
    const float* ln1g  = (const float*)d_in[14];
    const float* ln1b  = (const float*)d_in[15];
    const float* ln2g  = (const float*)d_in[16];
    const float* ln2b  = (const float*)d_in[17];

    char* ws = (char*)d_ws;
    // x: [0,8M)  q/val/hidden: [8,16M)  aw+ofb -> tmp -> ffnout: [16,24M)
    u16* x      = (u16*)(ws + 0);
    u16* q      = (u16*)(ws + 8 * MiB);
    u16* val    = (u16*)(ws + 8 * MiB);
    u16* hidden = (u16*)(ws + 8 * MiB);
    u16* aw     = (u16*)(ws + 16 * MiB);
    u16* ofb    = (u16*)(ws + 16 * MiB + 6553600);
    u16* tmp    = (u16*)(ws + 16 * MiB);
    u16* ffnout = (u16*)(ws + 16 * MiB);
    u16* attn   = (u16*)d_out;   // scratch in d_out bytes [0, 8 MiB): fully consumed
                                 // before the final f32 write overwrites it
    // prepacked weights live in d_out bytes [8 MiB, ~13.9 MiB) — also dead by final LN
    u16* wbuf   = (u16*)((char*)d_out + 8 * MiB);
    const size_t LSTR = 1474560;  // u16 elems per layer of packed weights

    const int ND = L_TOK * DMODEL;

    auto GM = [&](const u16* A, const u16* Whi, const u16* Wlo, const float* bias,
                  u16* C, int M, int K, int Npad, int Nact, int ldC, int relu) {
        hipLaunchKernelGGL(gemm_mfma, dim3(Npad / 64, M / 128), dim3(256), 0, stream,
                           A, Whi, Wlo, bias, C, K, Nact, ldC, relu);
    };
    auto PP = [&](const float* W, u16* hi, u16* lo, int K, int N, int Npad) {
        int tot = Npad * K;
        hipLaunchKernelGGL(prepack_kernel, dim3((tot + 255) / 256), dim3(256), 0, stream,
                           W, hi, lo, K, N, Npad);
    };

    // ---- prepack all weights (both layers) into d_out upper region ----
    // per-layer offsets (u16 elems):
    //   0       attn_hi (256x256)    65536  attn_lo
    //   131072  box_hi  (64x256)     147456 box_lo
    //   163840  v_hi    (256x256)    229376 v_lo
    //   294912  o_hi    (256x256)    360448 o_lo
    //   425984  w1_hi   (1024x256)   688128 w1_lo
    //   950272  w2_hi   (256x1024)   1212416 w2_lo
    for (int i = 0; i < 2; i++) {
        u16* wb = wbuf + (size_t)i * LSTR;
        PP(Wattn + (size_t)i * 51200,  wb + 0,      wb + 65536,   256, 200, 256);
        PP(Wbox  + (size_t)i * 8192,   wb + 131072, wb + 147456,  256, 32,  64);
        PP(Wv    + (size_t)i * 65536,  wb + 163840, wb + 229376,  256, 256, 256);
        PP(Wo    + (size_t)i * 65536,  wb + 294912, wb + 360448,  256, 256, 256);
        PP(W1    + (size_t)i * 262144, wb + 425984, wb + 688128,  256, 1024, 1024);
        PP(W2    + (size_t)i * 262144, wb + 950272, wb + 1212416, 1024, 256, 256);
    }

    // x = src^T  (natural (C,HW) -> (L,D))
    hipLaunchKernelGGL(xpose_kernel, dim3((ND + 255) / 256), dim3(256), 0, stream, srcp, x);

    for (int i = 0; i < 2; i++) {
        u16* wb = wbuf + (size_t)i * LSTR;

        hipLaunchKernelGGL(addq_kernel, dim3((ND + 255) / 256), dim3(256), 0, stream,
                           x, posp, q);

        GM(q, wb + 0,      wb + 65536,  battn + (size_t)i * 200, aw,  L_TOK, 256, 256, 200, 200, 0);
        GM(q, wb + 131072, wb + 147456, bbox  + (size_t)i * 32,  ofb, L_TOK, 256, 64,  32,  32,  0);
        hipLaunchKernelGGL(softmax_kernel, dim3((L_TOK * NHEAD + 255) / 256), dim3(256), 0,
                           stream, aw, L_TOK * NHEAD);

        GM(x, wb + 163840, wb + 229376, bv + (size_t)i * 256, val, L_TOK, 256, 256, 256, 256, 0);

        hipLaunchKernelGGL(sample_kernel, dim3(ND / 256), dim3(256), 0, stream,
                           val, aw, ofb, attn);

        GM(attn, wb + 294912, wb + 360448, bo + (size_t)i * 256, tmp, L_TOK, 256, 256, 256, 256, 0);

        hipLaunchKernelGGL(ln_naive, dim3(64), dim3(256), 0, stream,
                           x, tmp, ln1g + (size_t)i * 256, ln1b + (size_t)i * 256, x);

        for (int mc = 0; mc < 4; mc++) {
            const u16* xa = x + (size_t)mc * 4096 * 256;
            u16* ya = ffnout + (size_t)mc * 4096 * 256;
            GM(xa, wb + 425984, wb + 688128, b1 + (size_t)i * 1024, hidden, 4096, 256, 1024, 1024, 1024, 1);
            GM(hidden, wb + 950272, wb + 1212416, b2 + (size_t)i * 256, ya, 4096, 1024, 256, 256, 256, 0);
        }

        if (i == 0) {
            hipLaunchKernelGGL(ln_naive, dim3(64), dim3(256), 0, stream,
                               x, ffnout, ln2g, ln2b, x);
        } else {
            // FINAL: float32 output
            hipLaunchKernelGGL(ln_final_f32, dim3(64), dim3(256), 0, stream,
                               x, ffnout, ln2g + 256, ln2b + 256, outp);
        }
    }
}

// Round 2
// 870.103 us; speedup vs baseline: 8.7178x; 1.5376x over previous
//
#include <hip/hip_runtime.h>
#include <cstdint>
#include <cstddef>

typedef unsigned short u16;

#define L_TOK 16384
#define DMODEL 256
#define NHEAD 8
#define HDIM 32

typedef __attribute__((ext_vector_type(8))) short bf16x8;
typedef __attribute__((ext_vector_type(4))) float f32x4;
typedef __attribute__((ext_vector_type(4))) unsigned short u16x4;

__device__ __forceinline__ float bf2f(u16 u) {
    union { unsigned int i; float f; } v; v.i = ((unsigned int)u) << 16; return v.f;
}
__device__ __forceinline__ u16 f2bf(float f) {
    union { unsigned int i; float f; } v; v.f = f;
    unsigned int i = v.i;
    unsigned int r = (i + 0x7FFFu + ((i >> 16) & 1u)) >> 16;
    return (u16)r;
}

// ---------------- sentinel fill (FLOAT output) ----------------
__global__ __launch_bounds__(256) void fill_kernel(float* __restrict__ out, int n, float v) {
    int t = blockIdx.x * 256 + threadIdx.x;
    if (t < n) out[t] = v;
}

// x[l*256+d] = src[d*16384+l]  (src is (C, H*W) f32, natural layout)
__global__ __launch_bounds__(256) void xpose_kernel(const float* __restrict__ in,
                                                    u16* __restrict__ out) {
    int idx = blockIdx.x * 256 + threadIdx.x;
    if (idx >= L_TOK * DMODEL) return;
    int d = idx / L_TOK, l = idx - d * L_TOK;
    out[(size_t)l * DMODEL + d] = f2bf(in[idx]);
}

// q = x + pos^T
__global__ __launch_bounds__(256) void addq_kernel(const u16* __restrict__ x,
                                                   const float* __restrict__ p,
                                                   u16* __restrict__ q) {
    int idx = blockIdx.x * 256 + threadIdx.x;
    int l = idx >> 8, d = idx & 255;
    q[idx] = f2bf(bf2f(x[idx]) + p[(size_t)d * L_TOK + l]);
}

// ---------------- weight prepack: f32 [K][N] -> bf16 hi/lo transposed [Npad][K] ----
__global__ __launch_bounds__(256) void prepack_kernel(const float* __restrict__ W,
                                                      u16* __restrict__ hi,
                                                      u16* __restrict__ lo,
                                                      int K, int N, int Npad) {
    int idx = blockIdx.x * 256 + threadIdx.x;
    if (idx >= Npad * K) return;
    int n = idx / K, k = idx - n * K;
    float w = (n < N) ? W[(size_t)k * N + n] : 0.f;
    u16 h = f2bf(w);
    float rem = w - bf2f(h);
    hi[idx] = h;
    lo[idx] = f2bf(rem);
}

// ---------------- MFMA GEMM ----------------
// C[M][ldC](bf16) = A[M][K](bf16) @ (Whi+Wlo)^T  + bias, optional relu.
// Whi/Wlo are [Npad][K] (n-major). Tile: BM=128 x BN=64, BK=64, 4 waves.
// grid: (Npad/64, M/128)
#define BM 128
#define BN 64
#define BK 64

__global__ __launch_bounds__(256) void gemm_mfma(const u16* __restrict__ A,
                                                 const u16* __restrict__ Bhi,
                                                 const u16* __restrict__ Blo,
                                                 const float* __restrict__ bias,
                                                 u16* __restrict__ C,
                                                 int K, int Nact, int ldC, int relu) {
    __shared__ u16 lA[BM][BK + 8];
    __shared__ u16 lBh[BN][BK + 8];
    __shared__ u16 lBl[BN][BK + 8];

    const int tid  = threadIdx.x;
    const int lane = tid & 63;
    const int wave = tid >> 6;
    const int wm   = wave >> 1;   // 0..1, which 64-row half
    const int wn   = wave & 1;    // 0..1, which 32-col half
    const int row  = lane & 15;
    const int kch  = lane >> 4;   // 0..3

    const int m0 = blockIdx.y * BM;
    const int n0 = blockIdx.x * BN;

    f32x4 acc[4][2] = {};

    const int nkt = K / BK;
    for (int kt = 0; kt < nkt; ++kt) {
        const int kb0 = kt * BK;
        // stage A: 128x64, 16B per thread x 4
#pragma unroll
        for (int it = 0; it < 4; ++it) {
            int li = it * 256 + tid;
            int r = li >> 3, c8 = li & 7;
            bf16x8 v = *(const bf16x8*)(A + (size_t)(m0 + r) * K + kb0 + c8 * 8);
            *(bf16x8*)(&lA[r][c8 * 8]) = v;
        }
        // stage Bhi/Blo: 64x64 each
#pragma unroll
        for (int it = 0; it < 2; ++it) {
            int li = it * 256 + tid;
            int r = li >> 3, c8 = li & 7;
            bf16x8 vh = *(const bf16x8*)(Bhi + (size_t)(n0 + r) * K + kb0 + c8 * 8);
            bf16x8 vl = *(const bf16x8*)(Blo + (size_t)(n0 + r) * K + kb0 + c8 * 8);
            *(bf16x8*)(&lBh[r][c8 * 8]) = vh;
            *(bf16x8*)(&lBl[r][c8 * 8]) = vl;
        }
        __syncthreads();

#pragma unroll
        for (int kk = 0; kk < 2; ++kk) {
            const int kb = kk * 32 + kch * 8;
            bf16x8 af[4];
#pragma unroll
            for (int i = 0; i < 4; ++i)
                af[i] = *(const bf16x8*)(&lA[wm * 64 + i * 16 + row][kb]);
#pragma unroll
            for (int j = 0; j < 2; ++j) {
                bf16x8 bh = *(const bf16x8*)(&lBh[wn * 32 + j * 16 + row][kb]);
                bf16x8 bl = *(const bf16x8*)(&lBl[wn * 32 + j * 16 + row][kb]);
#pragma unroll
                for (int i = 0; i < 4; ++i) {
                    acc[i][j] = __builtin_amdgcn_mfma_f32_16x16x32_bf16(af[i], bh, acc[i][j], 0, 0, 0);
                    acc[i][j] = __builtin_amdgcn_mfma_f32_16x16x32_bf16(af[i], bl, acc[i][j], 0, 0, 0);
                }
            }
        }
        __syncthreads();
    }

    // epilogue: C/D layout col = lane&15, row = (lane>>4)*4 + reg
    const int cm0 = m0 + wm * 64 + (lane >> 4) * 4;
    const int cn0 = n0 + wn * 32 + (lane & 15);
#pragma unroll
    for (int j = 0; j < 2; ++j) {
        int cn = cn0 + j * 16;
        if (cn >= Nact) continue;
        float bv_ = bias[cn];
#pragma unroll
        for (int i = 0; i < 4; ++i) {
#pragma unroll
            for (int r = 0; r < 4; ++r) {
                float v = acc[i][j][r] + bv_;
                if (relu) v = fmaxf(v, 0.f);
                C[(size_t)(cm0 + i * 16 + r) * ldC + cn] = f2bf(v);
            }
        }
    }
}

__global__ __launch_bounds__(256) void softmax_kernel(u16* __restrict__ aw, int total) {
    int t = blockIdx.x * blockDim.x + threadIdx.x;
    if (t >= total) return;
    u16* pp = aw + (size_t)t * 25;
    float v[25];
    float mx = -1e30f;
    for (int k = 0; k < 25; k++) { v[k] = bf2f(pp[k]); mx = fmaxf(mx, v[k]); }
    float s = 0.f;
    for (int k = 0; k < 25; k++) { v[k] = __expf(v[k] - mx); s += v[k]; }
    float inv = 1.f / s;
    for (int k = 0; k < 25; k++) pp[k] = f2bf(v[k] * inv);
}

// one thread = (pair, 8-wide hd chunk). Weight math shared across 4 chunks only;
// val loads are 16B vector loads; output stores fully coalesced 16B/lane.
__global__ __launch_bounds__(256) void sample_kernel(const u16* __restrict__ val,
                                                     const u16* __restrict__ aw,
                                                     const u16* __restrict__ off,
                                                     u16* __restrict__ out) {
    int tid = blockIdx.x * 256 + threadIdx.x;
    int ch = tid & 3;             // hd chunk (8 elems)
    int pair = tid >> 2;          // l*NH + n
    int n = pair & 7;
    int l = pair >> 3;
    int iy = l >> 7, ix = l & 127;
    float cx = (ix + 0.5f) * (1.f / 128.f);
    float cy = (iy + 0.5f) * (1.f / 128.f);
    const u16* o = off + (size_t)pair * 4;
    float bx = cx + bf2f(o[0]) * (0.025f / 8.f);
    float by = cy + bf2f(o[1]) * (0.025f / 8.f);
    float bw = 0.025f + bf2f(o[2]) * (0.025f / 8.f);
    float bh = 0.025f + bf2f(o[3]) * (0.025f / 8.f);
    const u16* awp = aw + (size_t)pair * 25;
    const u16* vbase = val + n * 32 + ch * 8;
    float acc[8] = {};
    for (int k = 0; k < 25; k++) {
        float gx = (float)(k % 5 - 2) * 0.25f;
        float gy = (float)(k / 5 - 2) * 0.25f;
        float xx = (bx + bw * gx) * 128.f - 0.5f;
        float yy = (by + bh * gy) * 128.f - 0.5f;
        float x0 = floorf(xx), y0 = floorf(yy);
        float a_ = bf2f(awp[k]);
#pragma unroll
        for (int dy = 0; dy < 2; dy++) {
#pragma unroll
            for (int dx = 0; dx < 2; dx++) {
                float xi = x0 + dx, yi = y0 + dy;
                if (xi >= 0.f && xi < 128.f && yi >= 0.f && yi < 128.f) {
                    float w_ = (1.f - fabsf(xx - xi)) * (1.f - fabsf(yy - yi)) * a_;
                    int idx = (int)yi * 128 + (int)xi;
                    bf16x8 v = *(const bf16x8*)(vbase + (size_t)idx * 256);
#pragma unroll
                    for (int e = 0; e < 8; e++)
                        acc[e] += w_ * bf2f((u16)v[e]);
                }
            }
        }
    }
    bf16x8 ov;
#pragma unroll
    for (int e = 0; e < 8; e++) ov[e] = (short)f2bf(acc[e]);
    *(bf16x8*)(out + (size_t)l * 256 + n * 32 + ch * 8) = ov;
}

// ---------------- LayerNorm: one row per wave, fully in registers ----------------
// lane holds 4 of the 256 elements; 6-step shuffle butterfly for sum/sumsq.
__global__ __launch_bounds__(256) void ln_rows_bf16(const u16* __restrict__ xin,
                                                    const u16* __restrict__ delta,
                                                    const float* __restrict__ g,
                                                    const float* __restrict__ b,
                                                    u16* __restrict__ out) {
    int lane = threadIdx.x & 63;
    int row = blockIdx.x * 4 + (threadIdx.x >> 6);
    size_t base = (size_t)row * 256 + lane * 4;
    u16x4 xv = *(const u16x4*)(xin + base);
    u16x4 dv = *(const u16x4*)(delta + base);
    float v[4]; float s = 0.f, q = 0.f;
#pragma unroll
    for (int j = 0; j < 4; j++) {
        v[j] = bf2f(xv[j]) + bf2f(dv[j]);
        s += v[j]; q += v[j] * v[j];
    }
#pragma unroll
    for (int off = 1; off < 64; off <<= 1) {
        s += __shfl_xor(s, off, 64);
        q += __shfl_xor(q, off, 64);
    }
    float m = s * (1.f / 256.f);
    float var = q * (1.f / 256.f) - m * m;
    float r = rsqrtf(var + 1e-5f);
    f32x4 gv = *(const f32x4*)(g + lane * 4);
    f32x4 bv2 = *(const f32x4*)(b + lane * 4);
    u16x4 ov;
#pragma unroll
    for (int j = 0; j < 4; j++)
        ov[j] = f2bf((v[j] - m) * r * gv[j] + bv2[j]);
    *(u16x4*)(out + base) = ov;
}

// final LN writes FLOAT32 — d_out is the reference's output dtype (f32)
__global__ __launch_bounds__(256) void ln_rows_f32(const u16* __restrict__ xin,
                                                   const u16* __restrict__ delta,
                                                   const float* __restrict__ g,
                                                   const float* __restrict__ b,
                                                   float* __restrict__ out) {
    int lane = threadIdx.x & 63;
    int row = blockIdx.x * 4 + (threadIdx.x >> 6);
    size_t base = (size_t)row * 256 + lane * 4;
    u16x4 xv = *(const u16x4*)(xin + base);
    u16x4 dv = *(const u16x4*)(delta + base);
    float v[4]; float s = 0.f, q = 0.f;
#pragma unroll
    for (int j = 0; j < 4; j++) {
        v[j] = bf2f(xv[j]) + bf2f(dv[j]);
        s += v[j]; q += v[j] * v[j];
    }
#pragma unroll
    for (int off = 1; off < 64; off <<= 1) {
        s += __shfl_xor(s, off, 64);
        q += __shfl_xor(q, off, 64);
    }
    float m = s * (1.f / 256.f);
    float var = q * (1.f / 256.f) - m * m;
    float r = rsqrtf(var + 1e-5f);
    f32x4 gv = *(const f32x4*)(g + lane * 4);
    f32x4 bv2 = *(const f32x4*)(b + lane * 4);
    f32x4 ov;
#pragma unroll
    for (int j = 0; j < 4; j++)
        ov[j] = (v[j] - m) * r * gv[j] + bv2[j];
    *(f32x4*)(out + base) = ov;
}

extern "C" void kernel_launch(void* const* d_in, const int* in_sizes, int n_in,
                              void* d_out, int out_size, void* d_ws, size_t ws_size,
                              hipStream_t stream) {
    const size_t MiB = 1048576;
    float* outp = (float*)d_out;
    int fillg = (out_size + 255) / 256;

    // ---- environment sentinels ----
    const int exp_sizes[18] = {4194304, 4194304, 131072, 512, 16384, 64, 102400, 400,
                               131072, 512, 524288, 2048, 524288, 512, 512, 512, 512, 512};
    bool env_ok = (n_in == 18) && (ws_size >= 25 * MiB) && (out_size == 4194304);
    if (env_ok) for (int i = 0; i < 18; i++) env_ok = env_ok && (in_sizes[i] == exp_sizes[i]);
    if (!env_ok) {
        hipLaunchKernelGGL(fill_kernel, dim3(fillg), dim3(256), 0, stream, outp, out_size, 3000.f);
        return;
    }

    const float* srcp  = (const float*)d_in[0];
    const float* posp  = (const float*)d_in[1];
    const float* Wv    = (const float*)d_in[2];
    const float* bv    = (const float*)d_in[3];
    const float* Wbox  = (const float*)d_in[4];
    const float* bbox  = (const float*)d_in[5];
    const float* Wattn = (const float*)d_in[6];
    const float* battn = (const float*)d_in[7];
    const float* Wo    = (const float*)d_in[8];
    const float* bo    = (const float*)d_in[9];
    const float* W1    = (const float*)d_in[10];
    const float* b1    = (const float*)d_in[11];
    const float* W2    = (const float*)d_in[12];
    const float* b2    = (const float*)d_in[13];
    const float* ln1g  = (const float*)d_in[14];
    const float* ln1b  = (const float*)d_in[15];
    const float* ln2g  = (const float*)d_in[16];
    const float* ln2b  = (const float*)d_in[17];

    char* ws = (char*)d_ws;
    // x: [0,8M)  q/val/hidden: [8,16M)  aw+ofb -> tmp -> ffnout: [16,24M)
    u16* x      = (u16*)(ws + 0);
    u16* q      = (u16*)(ws + 8 * MiB);
    u16* val    = (u16*)(ws + 8 * MiB);
    u16* hidden = (u16*)(ws + 8 * MiB);
    u16* aw     = (u16*)(ws + 16 * MiB);
    u16* ofb    = (u16*)(ws + 16 * MiB + 6553600);
    u16* tmp    = (u16*)(ws + 16 * MiB);
    u16* ffnout = (u16*)(ws + 16 * MiB);
    u16* attn   = (u16*)d_out;   // scratch in d_out bytes [0, 8 MiB): fully consumed
                                 // before the final f32 write overwrites it
    // prepacked weights live in d_out bytes [8 MiB, ~13.9 MiB) — also dead by final LN
    u16* wbuf   = (u16*)((char*)d_out + 8 * MiB);
    const size_t LSTR = 1474560;  // u16 elems per layer of packed weights

    const int ND = L_TOK * DMODEL;

    auto GM = [&](const u16* A, const u16* Whi, const u16* Wlo, const float* bias,
                  u16* C, int M, int K, int Npad, int Nact, int ldC, int relu) {
        hipLaunchKernelGGL(gemm_mfma, dim3(Npad / 64, M / 128), dim3(256), 0, stream,
                           A, Whi, Wlo, bias, C, K, Nact, ldC, relu);
    };
    auto PP = [&](const float* W, u16* hi, u16* lo, int K, int N, int Npad) {
        int tot = Npad * K;
        hipLaunchKernelGGL(prepack_kernel, dim3((tot + 255) / 256), dim3(256), 0, stream,
                           W, hi, lo, K, N, Npad);
    };

    // ---- prepack all weights (both layers) into d_out upper region ----
    for (int i = 0; i < 2; i++) {
        u16* wb = wbuf + (size_t)i * LSTR;
        PP(Wattn + (size_t)i * 51200,  wb + 0,      wb + 65536,   256, 200, 256);
        PP(Wbox  + (size_t)i * 8192,   wb + 131072, wb + 147456,  256, 32,  64);
        PP(Wv    + (size_t)i * 65536,  wb + 163840, wb + 229376,  256, 256, 256);
        PP(Wo    + (size_t)i * 65536,  wb + 294912, wb + 360448,  256, 256, 256);
        PP(W1    + (size_t)i * 262144, wb + 425984, wb + 688128,  256, 1024, 1024);
        PP(W2    + (size_t)i * 262144, wb + 950272, wb + 1212416, 1024, 256, 256);
    }

    // x = src^T  (natural (C,HW) -> (L,D))
    hipLaunchKernelGGL(xpose_kernel, dim3((ND + 255) / 256), dim3(256), 0, stream, srcp, x);

    for (int i = 0; i < 2; i++) {
        u16* wb = wbuf + (size_t)i * LSTR;

        hipLaunchKernelGGL(addq_kernel, dim3((ND + 255) / 256), dim3(256), 0, stream,
                           x, posp, q);

        GM(q, wb + 0,      wb + 65536,  battn + (size_t)i * 200, aw,  L_TOK, 256, 256, 200, 200, 0);
        GM(q, wb + 131072, wb + 147456, bbox  + (size_t)i * 32,  ofb, L_TOK, 256, 64,  32,  32,  0);
        hipLaunchKernelGGL(softmax_kernel, dim3((L_TOK * NHEAD + 255) / 256), dim3(256), 0,
                           stream, aw, L_TOK * NHEAD);

        GM(x, wb + 163840, wb + 229376, bv + (size_t)i * 256, val, L_TOK, 256, 256, 256, 256, 0);

        hipLaunchKernelGGL(sample_kernel, dim3(L_TOK * NHEAD * 4 / 256), dim3(256), 0, stream,
                           val, aw, ofb, attn);

        GM(attn, wb + 294912, wb + 360448, bo + (size_t)i * 256, tmp, L_TOK, 256, 256, 256, 256, 0);

        hipLaunchKernelGGL(ln_rows_bf16, dim3(L_TOK / 4), dim3(256), 0, stream,
                           x, tmp, ln1g + (size_t)i * 256, ln1b + (size_t)i * 256, x);

        for (int mc = 0; mc < 4; mc++) {
            const u16* xa = x + (size_t)mc * 4096 * 256;
            u16* ya = ffnout + (size_t)mc * 4096 * 256;
            GM(xa, wb + 425984, wb + 688128, b1 + (size_t)i * 1024, hidden, 4096, 256, 1024, 1024, 1024, 1);
            GM(hidden, wb + 950272, wb + 1212416, b2 + (size_t)i * 256, ya, 4096, 1024, 256, 256, 256, 0);
        }

        if (i == 0) {
            hipLaunchKernelGGL(ln_rows_bf16, dim3(L_TOK / 4), dim3(256), 0, stream,
                               x, ffnout, ln2g, ln2b, x);
        } else {
            // FINAL: float32 output
            hipLaunchKernelGGL(ln_rows_f32, dim3(L_TOK / 4), dim3(256), 0, stream,
                               x, ffnout, ln2g + 256, ln2b + 256, outp);
        }
    }
}

// Round 3
// 680.745 us; speedup vs baseline: 11.1427x; 1.2782x over previous
//
#include <hip/hip_runtime.h>
#include <cstdint>
#include <cstddef>

typedef unsigned short u16;
typedef unsigned int u32;

#define L_TOK 16384
#define DMODEL 256
#define NHEAD 8
#define HDIM 32

typedef __attribute__((ext_vector_type(8))) short bf16x8;
typedef __attribute__((ext_vector_type(4))) float f32x4;
typedef __attribute__((ext_vector_type(4))) unsigned short u16x4;

__device__ __forceinline__ float bf2f(u16 u) {
    union { unsigned int i; float f; } v; v.i = ((unsigned int)u) << 16; return v.f;
}
__device__ __forceinline__ u16 f2bf(float f) {
    union { unsigned int i; float f; } v; v.f = f;
    unsigned int i = v.i;
    unsigned int r = (i + 0x7FFFu + ((i >> 16) & 1u)) >> 16;
    return (u16)r;
}

// direct global->LDS DMA, 16B per lane; LDS dest must be wave-uniform base + lane*16
__device__ __forceinline__ void gload16(const u16* g, u16* l) {
    __builtin_amdgcn_global_load_lds((const __attribute__((address_space(1))) u32*)g,
                                     (__attribute__((address_space(3))) u32*)l, 16, 0, 0);
}

// ---------------- sentinel fill (FLOAT output) ----------------
__global__ __launch_bounds__(256) void fill_kernel(float* __restrict__ out, int n, float v) {
    int t = blockIdx.x * 256 + threadIdx.x;
    if (t < n) out[t] = v;
}

// x[l*256+d] = src[d*16384+l]  (src is (C, H*W) f32, natural layout)
__global__ __launch_bounds__(256) void xpose_kernel(const float* __restrict__ in,
                                                    u16* __restrict__ out) {
    int idx = blockIdx.x * 256 + threadIdx.x;
    if (idx >= L_TOK * DMODEL) return;
    int d = idx / L_TOK, l = idx - d * L_TOK;
    out[(size_t)l * DMODEL + d] = f2bf(in[idx]);
}

// q = x + pos^T
__global__ __launch_bounds__(256) void addq_kernel(const u16* __restrict__ x,
                                                   const float* __restrict__ p,
                                                   u16* __restrict__ q) {
    int idx = blockIdx.x * 256 + threadIdx.x;
    int l = idx >> 8, d = idx & 255;
    q[idx] = f2bf(bf2f(x[idx]) + p[(size_t)d * L_TOK + l]);
}

// ---------------- weight prepack: f32 [K][N] -> bf16 hi/lo transposed [Npad][K] ----
__global__ __launch_bounds__(256) void prepack_kernel(const float* __restrict__ W,
                                                      u16* __restrict__ hi,
                                                      u16* __restrict__ lo,
                                                      int K, int N, int Npad) {
    int idx = blockIdx.x * 256 + threadIdx.x;
    if (idx >= Npad * K) return;
    int n = idx / K, k = idx - n * K;
    float w = (n < N) ? W[(size_t)k * N + n] : 0.f;
    u16 h = f2bf(w);
    float rem = w - bf2f(h);
    hi[idx] = h;
    lo[idx] = f2bf(rem);
}

// ---------------- MFMA GEMM (global_load_lds staging, linear LDS) ----------------
// C[M][ldC](bf16) = A[M][K](bf16) @ (Whi+Wlo)^T  + bias, optional relu.
// Whi/Wlo are [Npad][K] (n-major). Tile: BM=128 x BN=64, BK=64, 4 waves.
// grid: (Npad/64, M/128)
#define BM 128
#define BN 64
#define BK 64

__global__ __launch_bounds__(256) void gemm_mfma(const u16* __restrict__ A,
                                                 const u16* __restrict__ Bhi,
                                                 const u16* __restrict__ Blo,
                                                 const float* __restrict__ bias,
                                                 u16* __restrict__ C,
                                                 int K, int Nact, int ldC, int relu) {
    // linear layouts: elem offset for staging index li is li*8 (= (li>>3)*BK + (li&7)*8)
    __shared__ u16 lA[BM * BK];    // 16 KB
    __shared__ u16 lBh[BN * BK];   // 8 KB
    __shared__ u16 lBl[BN * BK];   // 8 KB

    const int tid  = threadIdx.x;
    const int lane = tid & 63;
    const int wave = tid >> 6;
    const int wm   = wave >> 1;   // 0..1, which 64-row half
    const int wn   = wave & 1;    // 0..1, which 32-col half
    const int row  = lane & 15;
    const int kch  = lane >> 4;   // 0..3

    const int m0 = blockIdx.y * BM;
    const int n0 = blockIdx.x * BN;

    // per-thread staging addresses: row chunk = tid>>3, col chunk = (tid&7)*8
    const u16* ga  = A   + (size_t)(m0 + (tid >> 3)) * K + (tid & 7) * 8;
    const u16* gbh = Bhi + (size_t)(n0 + (tid >> 3)) * K + (tid & 7) * 8;
    const u16* gbl = Blo + (size_t)(n0 + (tid >> 3)) * K + (tid & 7) * 8;
    u16* la  = lA  + tid * 8;
    u16* lbh = lBh + tid * 8;
    u16* lbl = lBl + tid * 8;

    f32x4 acc[4][2] = {};

    for (int kt = 0; kt < K; kt += BK) {
        // stage A: 128x64 = 4 chunks of (32 rows x 64 cols)
#pragma unroll
        for (int it = 0; it < 4; ++it)
            gload16(ga + kt + (size_t)it * 32 * K, la + it * 2048);
        // stage Bhi/Blo: 64x64 = 2 chunks each
#pragma unroll
        for (int it = 0; it < 2; ++it) {
            gload16(gbh + kt + (size_t)it * 32 * K, lbh + it * 2048);
            gload16(gbl + kt + (size_t)it * 32 * K, lbl + it * 2048);
        }
        __syncthreads();   // drains vmcnt -> LDS tiles ready

#pragma unroll
        for (int kk = 0; kk < 2; ++kk) {
            const int kb = kk * 32 + kch * 8;
            bf16x8 af[4];
#pragma unroll
            for (int i = 0; i < 4; ++i)
                af[i] = *(const bf16x8*)(&lA[(wm * 64 + i * 16 + row) * BK + kb]);
#pragma unroll
            for (int j = 0; j < 2; ++j) {
                bf16x8 bh = *(const bf16x8*)(&lBh[(wn * 32 + j * 16 + row) * BK + kb]);
                bf16x8 bl = *(const bf16x8*)(&lBl[(wn * 32 + j * 16 + row) * BK + kb]);
#pragma unroll
                for (int i = 0; i < 4; ++i) {
                    acc[i][j] = __builtin_amdgcn_mfma_f32_16x16x32_bf16(af[i], bh, acc[i][j], 0, 0, 0);
                    acc[i][j] = __builtin_amdgcn_mfma_f32_16x16x32_bf16(af[i], bl, acc[i][j], 0, 0, 0);
                }
            }
        }
        __syncthreads();   // all reads done before next stage overwrites
    }

    // epilogue: C/D layout col = lane&15, row = (lane>>4)*4 + reg
    const int cm0 = m0 + wm * 64 + (lane >> 4) * 4;
    const int cn0 = n0 + wn * 32 + (lane & 15);
#pragma unroll
    for (int j = 0; j < 2; ++j) {
        int cn = cn0 + j * 16;
        if (cn >= Nact) continue;
        float bv_ = bias[cn];
#pragma unroll
        for (int i = 0; i < 4; ++i) {
#pragma unroll
            for (int r = 0; r < 4; ++r) {
                float v = acc[i][j][r] + bv_;
                if (relu) v = fmaxf(v, 0.f);
                C[(size_t)(cm0 + i * 16 + r) * ldC + cn] = f2bf(v);
            }
        }
    }
}

__global__ __launch_bounds__(256) void softmax_kernel(u16* __restrict__ aw, int total) {
    int t = blockIdx.x * blockDim.x + threadIdx.x;
    if (t >= total) return;
    u16* pp = aw + (size_t)t * 25;
    float v[25];
    float mx = -1e30f;
    for (int k = 0; k < 25; k++) { v[k] = bf2f(pp[k]); mx = fmaxf(mx, v[k]); }
    float s = 0.f;
    for (int k = 0; k < 25; k++) { v[k] = __expf(v[k] - mx); s += v[k]; }
    float inv = 1.f / s;
    for (int k = 0; k < 25; k++) pp[k] = f2bf(v[k] * inv);
}

// one thread = (pair, 8-wide hd chunk). Weight math shared across 4 chunks only;
// val loads are 16B vector loads; output stores fully coalesced 16B/lane.
__global__ __launch_bounds__(256) void sample_kernel(const u16* __restrict__ val,
                                                     const u16* __restrict__ aw,
                                                     const u16* __restrict__ off,
                                                     u16* __restrict__ out) {
    int tid = blockIdx.x * 256 + threadIdx.x;
    int ch = tid & 3;             // hd chunk (8 elems)
    int pair = tid >> 2;          // l*NH + n
    int n = pair & 7;
    int l = pair >> 3;
    int iy = l >> 7, ix = l & 127;
    float cx = (ix + 0.5f) * (1.f / 128.f);
    float cy = (iy + 0.5f) * (1.f / 128.f);
    const u16* o = off + (size_t)pair * 4;
    float bx = cx + bf2f(o[0]) * (0.025f / 8.f);
    float by = cy + bf2f(o[1]) * (0.025f / 8.f);
    float bw = 0.025f + bf2f(o[2]) * (0.025f / 8.f);
    float bh = 0.025f + bf2f(o[3]) * (0.025f / 8.f);
    const u16* awp = aw + (size_t)pair * 25;
    const u16* vbase = val + n * 32 + ch * 8;
    float acc[8] = {};
    for (int k = 0; k < 25; k++) {
        float gx = (float)(k % 5 - 2) * 0.25f;
        float gy = (float)(k / 5 - 2) * 0.25f;
        float xx = (bx + bw * gx) * 128.f - 0.5f;
        float yy = (by + bh * gy) * 128.f - 0.5f;
        float x0 = floorf(xx), y0 = floorf(yy);
        float a_ = bf2f(awp[k]);
#pragma unroll
        for (int dy = 0; dy < 2; dy++) {
#pragma unroll
            for (int dx = 0; dx < 2; dx++) {
                float xi = x0 + dx, yi = y0 + dy;
                if (xi >= 0.f && xi < 128.f && yi >= 0.f && yi < 128.f) {
                    float w_ = (1.f - fabsf(xx - xi)) * (1.f - fabsf(yy - yi)) * a_;
                    int idx = (int)yi * 128 + (int)xi;
                    bf16x8 v = *(const bf16x8*)(vbase + (size_t)idx * 256);
#pragma unroll
                    for (int e = 0; e < 8; e++)
                        acc[e] += w_ * bf2f((u16)v[e]);
                }
            }
        }
    }
    bf16x8 ov;
#pragma unroll
    for (int e = 0; e < 8; e++) ov[e] = (short)f2bf(acc[e]);
    *(bf16x8*)(out + (size_t)l * 256 + n * 32 + ch * 8) = ov;
}

// ---------------- LayerNorm: one row per wave, fully in registers ----------------
__global__ __launch_bounds__(256) void ln_rows_bf16(const u16* __restrict__ xin,
                                                    const u16* __restrict__ delta,
                                                    const float* __restrict__ g,
                                                    const float* __restrict__ b,
                                                    u16* __restrict__ out) {
    int lane = threadIdx.x & 63;
    int row = blockIdx.x * 4 + (threadIdx.x >> 6);
    size_t base = (size_t)row * 256 + lane * 4;
    u16x4 xv = *(const u16x4*)(xin + base);
    u16x4 dv = *(const u16x4*)(delta + base);
    float v[4]; float s = 0.f, q = 0.f;
#pragma unroll
    for (int j = 0; j < 4; j++) {
        v[j] = bf2f(xv[j]) + bf2f(dv[j]);
        s += v[j]; q += v[j] * v[j];
    }
#pragma unroll
    for (int off = 1; off < 64; off <<= 1) {
        s += __shfl_xor(s, off, 64);
        q += __shfl_xor(q, off, 64);
    }
    float m = s * (1.f / 256.f);
    float var = q * (1.f / 256.f) - m * m;
    float r = rsqrtf(var + 1e-5f);
    f32x4 gv = *(const f32x4*)(g + lane * 4);
    f32x4 bv2 = *(const f32x4*)(b + lane * 4);
    u16x4 ov;
#pragma unroll
    for (int j = 0; j < 4; j++)
        ov[j] = f2bf((v[j] - m) * r * gv[j] + bv2[j]);
    *(u16x4*)(out + base) = ov;
}

// final LN writes FLOAT32 — d_out is the reference's output dtype (f32)
__global__ __launch_bounds__(256) void ln_rows_f32(const u16* __restrict__ xin,
                                                   const u16* __restrict__ delta,
                                                   const float* __restrict__ g,
                                                   const float* __restrict__ b,
                                                   float* __restrict__ out) {
    int lane = threadIdx.x & 63;
    int row = blockIdx.x * 4 + (threadIdx.x >> 6);
    size_t base = (size_t)row * 256 + lane * 4;
    u16x4 xv = *(const u16x4*)(xin + base);
    u16x4 dv = *(const u16x4*)(delta + base);
    float v[4]; float s = 0.f, q = 0.f;
#pragma unroll
    for (int j = 0; j < 4; j++) {
        v[j] = bf2f(xv[j]) + bf2f(dv[j]);
        s += v[j]; q += v[j] * v[j];
    }
#pragma unroll
    for (int off = 1; off < 64; off <<= 1) {
        s += __shfl_xor(s, off, 64);
        q += __shfl_xor(q, off, 64);
    }
    float m = s * (1.f / 256.f);
    float var = q * (1.f / 256.f) - m * m;
    float r = rsqrtf(var + 1e-5f);
    f32x4 gv = *(const f32x4*)(g + lane * 4);
    f32x4 bv2 = *(const f32x4*)(b + lane * 4);
    f32x4 ov;
#pragma unroll
    for (int j = 0; j < 4; j++)
        ov[j] = (v[j] - m) * r * gv[j] + bv2[j];
    *(f32x4*)(out + base) = ov;
}

extern "C" void kernel_launch(void* const* d_in, const int* in_sizes, int n_in,
                              void* d_out, int out_size, void* d_ws, size_t ws_size,
                              hipStream_t stream) {
    const size_t MiB = 1048576;
    float* outp = (float*)d_out;
    int fillg = (out_size + 255) / 256;

    // ---- environment sentinels ----
    const int exp_sizes[18] = {4194304, 4194304, 131072, 512, 16384, 64, 102400, 400,
                               131072, 512, 524288, 2048, 524288, 512, 512, 512, 512, 512};
    bool env_ok = (n_in == 18) && (ws_size >= 25 * MiB) && (out_size == 4194304);
    if (env_ok) for (int i = 0; i < 18; i++) env_ok = env_ok && (in_sizes[i] == exp_sizes[i]);
    if (!env_ok) {
        hipLaunchKernelGGL(fill_kernel, dim3(fillg), dim3(256), 0, stream, outp, out_size, 3000.f);
        return;
    }

    const float* srcp  = (const float*)d_in[0];
    const float* posp  = (const float*)d_in[1];
    const float* Wv    = (const float*)d_in[2];
    const float* bv    = (const float*)d_in[3];
    const float* Wbox  = (const float*)d_in[4];
    const float* bbox  = (const float*)d_in[5];
    const float* Wattn = (const float*)d_in[6];
    const float* battn = (const float*)d_in[7];
    const float* Wo    = (const float*)d_in[8];
    const float* bo    = (const float*)d_in[9];
    const float* W1    = (const float*)d_in[10];
    const float* b1    = (const float*)d_in[11];
    const float* W2    = (const float*)d_in[12];
    const float* b2    = (const float*)d_in[13];
    const float* ln1g  = (const float*)d_in[14];
    const float* ln1b  = (const float*)d_in[15];
    const float* ln2g  = (const float*)d_in[16];
    const float* ln2b  = (const float*)d_in[17];

    char* ws = (char*)d_ws;
    u16* x      = (u16*)(ws + 0);
    u16* q      = (u16*)(ws + 8 * MiB);
    u16* val    = (u16*)(ws + 8 * MiB);
    u16* hidden = (u16*)(ws + 8 * MiB);
    u16* aw     = (u16*)(ws + 16 * MiB);
    u16* ofb    = (u16*)(ws + 16 * MiB + 6553600);
    u16* tmp    = (u16*)(ws + 16 * MiB);
    u16* ffnout = (u16*)(ws + 16 * MiB);
    u16* attn   = (u16*)d_out;   // scratch in d_out bytes [0, 8 MiB)
    u16* wbuf   = (u16*)((char*)d_out + 8 * MiB);
    const size_t LSTR = 1474560;  // u16 elems per layer of packed weights

    const int ND = L_TOK * DMODEL;

    auto GM = [&](const u16* A, const u16* Whi, const u16* Wlo, const float* bias,
                  u16* C, int M, int K, int Npad, int Nact, int ldC, int relu) {
        hipLaunchKernelGGL(gemm_mfma, dim3(Npad / 64, M / 128), dim3(256), 0, stream,
                           A, Whi, Wlo, bias, C, K, Nact, ldC, relu);
    };
    auto PP = [&](const float* W, u16* hi, u16* lo, int K, int N, int Npad) {
        int tot = Npad * K;
        hipLaunchKernelGGL(prepack_kernel, dim3((tot + 255) / 256), dim3(256), 0, stream,
                           W, hi, lo, K, N, Npad);
    };

    // ---- prepack all weights (both layers) into d_out upper region ----
    for (int i = 0; i < 2; i++) {
        u16* wb = wbuf + (size_t)i * LSTR;
        PP(Wattn + (size_t)i * 51200,  wb + 0,      wb + 65536,   256, 200, 256);
        PP(Wbox  + (size_t)i * 8192,   wb + 131072, wb + 147456,  256, 32,  64);
        PP(Wv    + (size_t)i * 65536,  wb + 163840, wb + 229376,  256, 256, 256);
        PP(Wo    + (size_t)i * 65536,  wb + 294912, wb + 360448,  256, 256, 256);
        PP(W1    + (size_t)i * 262144, wb + 425984, wb + 688128,  256, 1024, 1024);
        PP(W2    + (size_t)i * 262144, wb + 950272, wb + 1212416, 1024, 256, 256);
    }

    // x = src^T  (natural (C,HW) -> (L,D))
    hipLaunchKernelGGL(xpose_kernel, dim3((ND + 255) / 256), dim3(256), 0, stream, srcp, x);

    for (int i = 0; i < 2; i++) {
        u16* wb = wbuf + (size_t)i * LSTR;

        hipLaunchKernelGGL(addq_kernel, dim3((ND + 255) / 256), dim3(256), 0, stream,
                           x, posp, q);

        GM(q, wb + 0,      wb + 65536,  battn + (size_t)i * 200, aw,  L_TOK, 256, 256, 200, 200, 0);
        GM(q, wb + 131072, wb + 147456, bbox  + (size_t)i * 32,  ofb, L_TOK, 256, 64,  32,  32,  0);
        hipLaunchKernelGGL(softmax_kernel, dim3((L_TOK * NHEAD + 255) / 256), dim3(256), 0,
                           stream, aw, L_TOK * NHEAD);

        GM(x, wb + 163840, wb + 229376, bv + (size_t)i * 256, val, L_TOK, 256, 256, 256, 256, 0);

        hipLaunchKernelGGL(sample_kernel, dim3(L_TOK * NHEAD * 4 / 256), dim3(256), 0, stream,
                           val, aw, ofb, attn);

        GM(attn, wb + 294912, wb + 360448, bo + (size_t)i * 256, tmp, L_TOK, 256, 256, 256, 256, 0);

        hipLaunchKernelGGL(ln_rows_bf16, dim3(L_TOK / 4), dim3(256), 0, stream,
                           x, tmp, ln1g + (size_t)i * 256, ln1b + (size_t)i * 256, x);

        for (int mc = 0; mc < 4; mc++) {
            const u16* xa = x + (size_t)mc * 4096 * 256;
            u16* ya = ffnout + (size_t)mc * 4096 * 256;
            GM(xa, wb + 425984, wb + 688128, b1 + (size_t)i * 1024, hidden, 4096, 256, 1024, 1024, 1024, 1);
            GM(hidden, wb + 950272, wb + 1212416, b2 + (size_t)i * 256, ya, 4096, 1024, 256, 256, 256, 0);
        }

        if (i == 0) {
            hipLaunchKernelGGL(ln_rows_bf16, dim3(L_TOK / 4), dim3(256), 0, stream,
                               x, ffnout, ln2g, ln2b, x);
        } else {
            // FINAL: float32 output
            hipLaunchKernelGGL(ln_rows_f32, dim3(L_TOK / 4), dim3(256), 0, stream,
                               x, ffnout, ln2g + 256, ln2b + 256, outp);
        }
    }
}

// Round 5
// 588.266 us; speedup vs baseline: 12.8945x; 1.1572x over previous
//
#include <hip/hip_runtime.h>
#include <cstdint>
#include <cstddef>

typedef unsigned short u16;
typedef unsigned int u32;

#define L_TOK 16384
#define DMODEL 256
#define NHEAD 8
#define HDIM 32

typedef __attribute__((ext_vector_type(8))) short bf16x8;
typedef __attribute__((ext_vector_type(4))) float f32x4;
typedef __attribute__((ext_vector_type(4))) unsigned short u16x4;

__device__ __forceinline__ float bf2f(u16 u) {
    union { unsigned int i; float f; } v; v.i = ((unsigned int)u) << 16; return v.f;
}
__device__ __forceinline__ u16 f2bf(float f) {
    union { unsigned int i; float f; } v; v.f = f;
    unsigned int i = v.i;
    unsigned int r = (i + 0x7FFFu + ((i >> 16) & 1u)) >> 16;
    return (u16)r;
}

// direct global->LDS DMA, 16B per lane; LDS dest is wave-uniform base + lane*16
__device__ __forceinline__ void gload16(const u16* g, u16* l) {
    __builtin_amdgcn_global_load_lds((const __attribute__((address_space(1))) u32*)g,
                                     (__attribute__((address_space(3))) u32*)l, 16, 0, 0);
}

// ---------------- sentinel fill (FLOAT output) ----------------
__global__ __launch_bounds__(256) void fill_kernel(float* __restrict__ out, int n, float v) {
    int t = blockIdx.x * 256 + threadIdx.x;
    if (t < n) out[t] = v;
}

// x[l*256+d] = src[d*16384+l]  (src is (C, H*W) f32, natural layout)
__global__ __launch_bounds__(256) void xpose_kernel(const float* __restrict__ in,
                                                    u16* __restrict__ out) {
    int idx = blockIdx.x * 256 + threadIdx.x;
    if (idx >= L_TOK * DMODEL) return;
    int d = idx / L_TOK, l = idx - d * L_TOK;
    out[(size_t)l * DMODEL + d] = f2bf(in[idx]);
}

// q = x + pos^T
__global__ __launch_bounds__(256) void addq_kernel(const u16* __restrict__ x,
                                                   const float* __restrict__ p,
                                                   u16* __restrict__ q) {
    int idx = blockIdx.x * 256 + threadIdx.x;
    int l = idx >> 8, d = idx & 255;
    q[idx] = f2bf(bf2f(x[idx]) + p[(size_t)d * L_TOK + l]);
}

// ---------------- weight prepack: f32 [K][N] -> bf16 hi/lo transposed [Npad][K] ----
__global__ __launch_bounds__(256) void prepack_kernel(const float* __restrict__ W,
                                                      u16* __restrict__ hi,
                                                      u16* __restrict__ lo,
                                                      int K, int N, int Npad) {
    int idx = blockIdx.x * 256 + threadIdx.x;
    if (idx >= Npad * K) return;
    int n = idx / K, k = idx - n * K;
    float w = (n < N) ? W[(size_t)k * N + n] : 0.f;
    u16 h = f2bf(w);
    float rem = w - bf2f(h);
    hi[idx] = h;
    lo[idx] = f2bf(rem);
}

// ---------------- MFMA GEMM: pure-HIP 2-phase double-buffer (T3 minimum recipe) ----
// C[M][ldC](bf16) = A[M][K](bf16) @ (Whi+Wlo)^T + bias, optional relu.
// Whi/Wlo are [Npad][K] (n-major). BN=64, BK=64, 4 waves (2x2). grid (Npad/64, M/BMv).
// Per iter: prefetch tile t+1 into other buffer -> compute tile t -> __syncthreads()
// (implicit vmcnt(0) drains the prefetch AFTER compute: load latency fully overlapped).
#define BN 64
#define BK 64

template<int BMv>
__global__ __launch_bounds__(256) void gemm_mfma(const u16* __restrict__ A,
                                                 const u16* __restrict__ Bhi,
                                                 const u16* __restrict__ Blo,
                                                 const float* __restrict__ bias,
                                                 u16* __restrict__ C,
                                                 int K, int Nact, int ldC, int relu) {
    constexpr int ASZ = BMv * BK;          // u16 elems
    constexpr int BSZ = BN * BK;           // 4096
    constexpr int ACH = BMv / 32;          // A stage chunks (256 thr * 8 elems = 32 rows)
    constexpr int NI  = BMv / 32;          // 16-row tiles per wave half
    __shared__ __align__(16) u16 lds[2][ASZ + 2 * BSZ];  // BMv=128: 64 KB; BMv=64: 48 KB

    const int tid  = threadIdx.x;
    const int lane = tid & 63;
    const int wave = tid >> 6;
    const int wm = wave >> 1, wn = wave & 1;
    const int row = lane & 15, kch = lane >> 4;
    const int m0 = blockIdx.y * BMv;
    const int n0 = blockIdx.x * BN;

    // per-thread staging addresses (linear LDS: elem offset li*8, li = it*256+tid)
    const u16* ga  = A   + (size_t)(m0 + (tid >> 3)) * K + (tid & 7) * 8;
    const u16* gbh = Bhi + (size_t)(n0 + (tid >> 3)) * K + (tid & 7) * 8;
    const u16* gbl = Blo + (size_t)(n0 + (tid >> 3)) * K + (tid & 7) * 8;

    f32x4 acc[NI][2] = {};
    const int nkt = K / BK;

    auto stage = [&](int kt, int buf) {
        u16* lb = &lds[buf][0];
        const int ko = kt * BK;
#pragma unroll
        for (int it = 0; it < ACH; ++it)
            gload16(ga + ko + (size_t)it * 32 * K, lb + tid * 8 + it * 2048);
#pragma unroll
        for (int it = 0; it < 2; ++it) {
            gload16(gbh + ko + (size_t)it * 32 * K, lb + ASZ + tid * 8 + it * 2048);
            gload16(gbl + ko + (size_t)it * 32 * K, lb + ASZ + BSZ + tid * 8 + it * 2048);
        }
    };

    stage(0, 0);
    __syncthreads();                      // tile 0 ready
    for (int t = 0; t < nkt; ++t) {
        const int cur = t & 1;
        if (t + 1 < nkt) stage(t + 1, cur ^ 1);   // prefetch next tile (other buffer)

        const u16* lb = &lds[cur][0];
#pragma unroll
        for (int kk = 0; kk < 2; ++kk) {
            const int kb = kk * 32 + kch * 8;
            bf16x8 af[NI];
#pragma unroll
            for (int i = 0; i < NI; ++i)
                af[i] = *(const bf16x8*)(lb + (wm * (BMv / 2) + i * 16 + row) * BK + kb);
#pragma unroll
            for (int j = 0; j < 2; ++j) {
                bf16x8 bh = *(const bf16x8*)(lb + ASZ + (wn * 32 + j * 16 + row) * BK + kb);
                bf16x8 bl = *(const bf16x8*)(lb + ASZ + BSZ + (wn * 32 + j * 16 + row) * BK + kb);
#pragma unroll
                for (int i = 0; i < NI; ++i) {
                    acc[i][j] = __builtin_amdgcn_mfma_f32_16x16x32_bf16(af[i], bh, acc[i][j], 0, 0, 0);
                    acc[i][j] = __builtin_amdgcn_mfma_f32_16x16x32_bf16(af[i], bl, acc[i][j], 0, 0, 0);
                }
            }
        }
        __syncthreads();   // drains prefetch (vmcnt 0) + joins reads; next buffer ready
    }

    // epilogue: C/D layout col = lane&15, row = (lane>>4)*4 + reg
    const int cm0 = m0 + wm * (BMv / 2) + (lane >> 4) * 4;
    const int cn0 = n0 + wn * 32 + (lane & 15);
#pragma unroll
    for (int j = 0; j < 2; ++j) {
        int cn = cn0 + j * 16;
        if (cn >= Nact) continue;
        float bv_ = bias[cn];
#pragma unroll
        for (int i = 0; i < NI; ++i) {
#pragma unroll
            for (int r = 0; r < 4; ++r) {
                float v = acc[i][j][r] + bv_;
                if (relu) v = fmaxf(v, 0.f);
                C[(size_t)(cm0 + i * 16 + r) * ldC + cn] = f2bf(v);
            }
        }
    }
}

__global__ __launch_bounds__(256) void softmax_kernel(u16* __restrict__ aw, int total) {
    int t = blockIdx.x * blockDim.x + threadIdx.x;
    if (t >= total) return;
    u16* pp = aw + (size_t)t * 25;
    float v[25];
    float mx = -1e30f;
    for (int k = 0; k < 25; k++) { v[k] = bf2f(pp[k]); mx = fmaxf(mx, v[k]); }
    float s = 0.f;
    for (int k = 0; k < 25; k++) { v[k] = __expf(v[k] - mx); s += v[k]; }
    float inv = 1.f / s;
    for (int k = 0; k < 25; k++) pp[k] = f2bf(v[k] * inv);
}

// one thread = (pair, 8-wide hd chunk); branchless taps (clamped idx, zeroed weight)
__global__ __launch_bounds__(256) void sample_kernel(const u16* __restrict__ val,
                                                     const u16* __restrict__ aw,
                                                     const u16* __restrict__ off,
                                                     u16* __restrict__ out) {
    int tid = blockIdx.x * 256 + threadIdx.x;
    int ch = tid & 3;             // hd chunk (8 elems)
    int pair = tid >> 2;          // l*NH + n
    int n = pair & 7;
    int l = pair >> 3;
    int iy = l >> 7, ix = l & 127;
    float cx = (ix + 0.5f) * (1.f / 128.f);
    float cy = (iy + 0.5f) * (1.f / 128.f);
    const u16* o = off + (size_t)pair * 4;
    float bx = cx + bf2f(o[0]) * (0.025f / 8.f);
    float by = cy + bf2f(o[1]) * (0.025f / 8.f);
    float bw = 0.025f + bf2f(o[2]) * (0.025f / 8.f);
    float bh = 0.025f + bf2f(o[3]) * (0.025f / 8.f);
    const u16* awp = aw + (size_t)pair * 25;
    const u16* vbase = val + n * 32 + ch * 8;
    float acc[8] = {};
    for (int k = 0; k < 25; k++) {
        float gx = (float)(k % 5 - 2) * 0.25f;
        float gy = (float)(k / 5 - 2) * 0.25f;
        float xx = (bx + bw * gx) * 128.f - 0.5f;
        float yy = (by + bh * gy) * 128.f - 0.5f;
        float x0 = floorf(xx), y0 = floorf(yy);
        float a_ = bf2f(awp[k]);
#pragma unroll
        for (int dy = 0; dy < 2; dy++) {
#pragma unroll
            for (int dx = 0; dx < 2; dx++) {
                float xi = x0 + dx, yi = y0 + dy;
                float w_ = (1.f - fabsf(xx - xi)) * (1.f - fabsf(yy - yi)) * a_;
                bool valid = (xi >= 0.f) & (xi < 128.f) & (yi >= 0.f) & (yi < 128.f);
                w_ = valid ? w_ : 0.f;
                int ixi = min(max((int)xi, 0), 127);
                int iyi = min(max((int)yi, 0), 127);
                int idx = iyi * 128 + ixi;
                bf16x8 v = *(const bf16x8*)(vbase + (size_t)idx * 256);
#pragma unroll
                for (int e = 0; e < 8; e++)
                    acc[e] += w_ * bf2f((u16)v[e]);
            }
        }
    }
    bf16x8 ov;
#pragma unroll
    for (int e = 0; e < 8; e++) ov[e] = (short)f2bf(acc[e]);
    *(bf16x8*)(out + (size_t)l * 256 + n * 32 + ch * 8) = ov;
}

// ---------------- LayerNorm: one row per wave, fully in registers ----------------
__global__ __launch_bounds__(256) void ln_rows_bf16(const u16* __restrict__ xin,
                                                    const u16* __restrict__ delta,
                                                    const float* __restrict__ g,
                                                    const float* __restrict__ b,
                                                    u16* __restrict__ out) {
    int lane = threadIdx.x & 63;
    int row = blockIdx.x * 4 + (threadIdx.x >> 6);
    size_t base = (size_t)row * 256 + lane * 4;
    u16x4 xv = *(const u16x4*)(xin + base);
    u16x4 dv = *(const u16x4*)(delta + base);
    float v[4]; float s = 0.f, q = 0.f;
#pragma unroll
    for (int j = 0; j < 4; j++) {
        v[j] = bf2f(xv[j]) + bf2f(dv[j]);
        s += v[j]; q += v[j] * v[j];
    }
#pragma unroll
    for (int off = 1; off < 64; off <<= 1) {
        s += __shfl_xor(s, off, 64);
        q += __shfl_xor(q, off, 64);
    }
    float m = s * (1.f / 256.f);
    float var = q * (1.f / 256.f) - m * m;
    float r = rsqrtf(var + 1e-5f);
    f32x4 gv = *(const f32x4*)(g + lane * 4);
    f32x4 bv2 = *(const f32x4*)(b + lane * 4);
    u16x4 ov;
#pragma unroll
    for (int j = 0; j < 4; j++)
        ov[j] = f2bf((v[j] - m) * r * gv[j] + bv2[j]);
    *(u16x4*)(out + base) = ov;
}

// final LN writes FLOAT32 — d_out is the reference's output dtype (f32)
__global__ __launch_bounds__(256) void ln_rows_f32(const u16* __restrict__ xin,
                                                   const u16* __restrict__ delta,
                                                   const float* __restrict__ g,
                                                   const float* __restrict__ b,
                                                   float* __restrict__ out) {
    int lane = threadIdx.x & 63;
    int row = blockIdx.x * 4 + (threadIdx.x >> 6);
    size_t base = (size_t)row * 256 + lane * 4;
    u16x4 xv = *(const u16x4*)(xin + base);
    u16x4 dv = *(const u16x4*)(delta + base);
    float v[4]; float s = 0.f, q = 0.f;
#pragma unroll
    for (int j = 0; j < 4; j++) {
        v[j] = bf2f(xv[j]) + bf2f(dv[j]);
        s += v[j]; q += v[j] * v[j];
    }
#pragma unroll
    for (int off = 1; off < 64; off <<= 1) {
        s += __shfl_xor(s, off, 64);
        q += __shfl_xor(q, off, 64);
    }
    float m = s * (1.f / 256.f);
    float var = q * (1.f / 256.f) - m * m;
    float r = rsqrtf(var + 1e-5f);
    f32x4 gv = *(const f32x4*)(g + lane * 4);
    f32x4 bv2 = *(const f32x4*)(b + lane * 4);
    f32x4 ov;
#pragma unroll
    for (int j = 0; j < 4; j++)
        ov[j] = (v[j] - m) * r * gv[j] + bv2[j];
    *(f32x4*)(out + base) = ov;
}

extern "C" void kernel_launch(void* const* d_in, const int* in_sizes, int n_in,
                              void* d_out, int out_size, void* d_ws, size_t ws_size,
                              hipStream_t stream) {
    const size_t MiB = 1048576;
    float* outp = (float*)d_out;
    int fillg = (out_size + 255) / 256;

    // ---- environment sentinels ----
    const int exp_sizes[18] = {4194304, 4194304, 131072, 512, 16384, 64, 102400, 400,
                               131072, 512, 524288, 2048, 524288, 512, 512, 512, 512, 512};
    bool env_ok = (n_in == 18) && (ws_size >= 25 * MiB) && (out_size == 4194304);
    if (env_ok) for (int i = 0; i < 18; i++) env_ok = env_ok && (in_sizes[i] == exp_sizes[i]);
    if (!env_ok) {
        hipLaunchKernelGGL(fill_kernel, dim3(fillg), dim3(256), 0, stream, outp, out_size, 3000.f);
        return;
    }

    const float* srcp  = (const float*)d_in[0];
    const float* posp  = (const float*)d_in[1];
    const float* Wv    = (const float*)d_in[2];
    const float* bv    = (const float*)d_in[3];
    const float* Wbox  = (const float*)d_in[4];
    const float* bbox  = (const float*)d_in[5];
    const float* Wattn = (const float*)d_in[6];
    const float* battn = (const float*)d_in[7];
    const float* Wo    = (const float*)d_in[8];
    const float* bo    = (const float*)d_in[9];
    const float* W1    = (const float*)d_in[10];
    const float* b1    = (const float*)d_in[11];
    const float* W2    = (const float*)d_in[12];
    const float* b2    = (const float*)d_in[13];
    const float* ln1g  = (const float*)d_in[14];
    const float* ln1b  = (const float*)d_in[15];
    const float* ln2g  = (const float*)d_in[16];
    const float* ln2b  = (const float*)d_in[17];

    char* ws = (char*)d_ws;
    u16* x      = (u16*)(ws + 0);
    u16* q      = (u16*)(ws + 8 * MiB);
    u16* val    = (u16*)(ws + 8 * MiB);
    u16* hidden = (u16*)(ws + 8 * MiB);
    u16* aw     = (u16*)(ws + 16 * MiB);
    u16* ofb    = (u16*)(ws + 16 * MiB + 6553600);
    u16* tmp    = (u16*)(ws + 16 * MiB);
    u16* ffnout = (u16*)(ws + 16 * MiB);
    u16* attn   = (u16*)d_out;   // scratch in d_out bytes [0, 8 MiB)
    u16* wbuf   = (u16*)((char*)d_out + 8 * MiB);
    const size_t LSTR = 1474560;  // u16 elems per layer of packed weights

    const int ND = L_TOK * DMODEL;

    // small=false: BM=128. small=true: BM=64 (keeps grid >= 256 blocks for N=256/64)
    auto GM = [&](const u16* A, const u16* Whi, const u16* Wlo, const float* bias,
                  u16* C, int M, int K, int Npad, int Nact, int ldC, int relu, bool small) {
        if (small)
            hipLaunchKernelGGL((gemm_mfma<64>), dim3(Npad / 64, M / 64), dim3(256), 0, stream,
                               A, Whi, Wlo, bias, C, K, Nact, ldC, relu);
        else
            hipLaunchKernelGGL((gemm_mfma<128>), dim3(Npad / 64, M / 128), dim3(256), 0, stream,
                               A, Whi, Wlo, bias, C, K, Nact, ldC, relu);
    };
    auto PP = [&](const float* W, u16* hi, u16* lo, int K, int N, int Npad) {
        int tot = Npad * K;
        hipLaunchKernelGGL(prepack_kernel, dim3((tot + 255) / 256), dim3(256), 0, stream,
                           W, hi, lo, K, N, Npad);
    };

    // ---- prepack all weights (both layers) into d_out upper region ----
    for (int i = 0; i < 2; i++) {
        u16* wb = wbuf + (size_t)i * LSTR;
        PP(Wattn + (size_t)i * 51200,  wb + 0,      wb + 65536,   256, 200, 256);
        PP(Wbox  + (size_t)i * 8192,   wb + 131072, wb + 147456,  256, 32,  64);
        PP(Wv    + (size_t)i * 65536,  wb + 163840, wb + 229376,  256, 256, 256);
        PP(Wo    + (size_t)i * 65536,  wb + 294912, wb + 360448,  256, 256, 256);
        PP(W1    + (size_t)i * 262144, wb + 425984, wb + 688128,  256, 1024, 1024);
        PP(W2    + (size_t)i * 262144, wb + 950272, wb + 1212416, 1024, 256, 256);
    }

    // x = src^T  (natural (C,HW) -> (L,D))
    hipLaunchKernelGGL(xpose_kernel, dim3((ND + 255) / 256), dim3(256), 0, stream, srcp, x);

    for (int i = 0; i < 2; i++) {
        u16* wb = wbuf + (size_t)i * LSTR;

        hipLaunchKernelGGL(addq_kernel, dim3((ND + 255) / 256), dim3(256), 0, stream,
                           x, posp, q);

        GM(q, wb + 0,      wb + 65536,  battn + (size_t)i * 200, aw,  L_TOK, 256, 256, 200, 200, 0, false);
        GM(q, wb + 131072, wb + 147456, bbox  + (size_t)i * 32,  ofb, L_TOK, 256, 64,  32,  32,  0, true);
        hipLaunchKernelGGL(softmax_kernel, dim3((L_TOK * NHEAD + 255) / 256), dim3(256), 0,
                           stream, aw, L_TOK * NHEAD);

        GM(x, wb + 163840, wb + 229376, bv + (size_t)i * 256, val, L_TOK, 256, 256, 256, 256, 0, false);

        hipLaunchKernelGGL(sample_kernel, dim3(L_TOK * NHEAD * 4 / 256), dim3(256), 0, stream,
                           val, aw, ofb, attn);

        GM(attn, wb + 294912, wb + 360448, bo + (size_t)i * 256, tmp, L_TOK, 256, 256, 256, 256, 0, false);

        hipLaunchKernelGGL(ln_rows_bf16, dim3(L_TOK / 4), dim3(256), 0, stream,
                           x, tmp, ln1g + (size_t)i * 256, ln1b + (size_t)i * 256, x);

        for (int mc = 0; mc < 4; mc++) {
            const u16* xa = x + (size_t)mc * 4096 * 256;
            u16* ya = ffnout + (size_t)mc * 4096 * 256;
            GM(xa, wb + 425984, wb + 688128, b1 + (size_t)i * 1024, hidden, 4096, 256, 1024, 1024, 1024, 1, false);
            GM(hidden, wb + 950272, wb + 1212416, b2 + (size_t)i * 256, ya, 4096, 1024, 256, 256, 256, 0, true);
        }

        if (i == 0) {
            hipLaunchKernelGGL(ln_rows_bf16, dim3(L_TOK / 4), dim3(256), 0, stream,
                               x, ffnout, ln2g, ln2b, x);
        } else {
            // FINAL: float32 output
            hipLaunchKernelGGL(ln_rows_f32, dim3(L_TOK / 4), dim3(256), 0, stream,
                               x, ffnout, ln2g + 256, ln2b + 256, outp);
        }
    }
}

// Round 6
// 521.647 us; speedup vs baseline: 14.5412x; 1.1277x over previous
//
#include <hip/hip_runtime.h>
#include <cstdint>
#include <cstddef>

typedef unsigned short u16;
typedef unsigned int u32;

#define L_TOK 16384
#define DMODEL 256
#define NHEAD 8
#define HDIM 32

typedef __attribute__((ext_vector_type(8))) short bf16x8;
typedef __attribute__((ext_vector_type(4))) float f32x4;
typedef __attribute__((ext_vector_type(4))) unsigned short u16x4;

__device__ __forceinline__ float bf2f(u16 u) {
    union { unsigned int i; float f; } v; v.i = ((unsigned int)u) << 16; return v.f;
}
__device__ __forceinline__ u16 f2bf(float f) {
    union { unsigned int i; float f; } v; v.f = f;
    unsigned int i = v.i;
    unsigned int r = (i + 0x7FFFu + ((i >> 16) & 1u)) >> 16;
    return (u16)r;
}

// direct global->LDS DMA, 16B per lane; LDS dest is wave-uniform base + lane*16
__device__ __forceinline__ void gload16(const u16* g, u16* l) {
    __builtin_amdgcn_global_load_lds((const __attribute__((address_space(1))) u32*)g,
                                     (__attribute__((address_space(3))) u32*)l, 16, 0, 0);
}

// ---------------- sentinel fill (FLOAT output) ----------------
__global__ __launch_bounds__(256) void fill_kernel(float* __restrict__ out, int n, float v) {
    int t = blockIdx.x * 256 + threadIdx.x;
    if (t < n) out[t] = v;
}

// ---------------- tiled transpose: out[l][d](bf16) = in[d][l](f32), coalesced both sides
__global__ __launch_bounds__(256) void xpose_tiled(const float* __restrict__ in,
                                                   u16* __restrict__ out) {
    __shared__ float t[64][65];
    int d0 = blockIdx.x * 64, l0 = blockIdx.y * 64;
    int c = threadIdx.x & 63, r4 = threadIdx.x >> 6;
#pragma unroll
    for (int it = 0; it < 16; ++it) {
        int r = it * 4 + r4;
        t[r][c] = in[(size_t)(d0 + r) * L_TOK + l0 + c];
    }
    __syncthreads();
#pragma unroll
    for (int it = 0; it < 16; ++it) {
        int r = it * 4 + r4;
        out[(size_t)(l0 + r) * DMODEL + d0 + c] = f2bf(t[c][r]);
    }
}

// ---------------- q[l][d] = x[l][d] + pos[d][l], tiled (pos stays f32) ----------------
__global__ __launch_bounds__(256) void addq_tiled(const u16* __restrict__ x,
                                                  const float* __restrict__ p,
                                                  u16* __restrict__ q) {
    __shared__ float t[64][65];
    int d0 = blockIdx.x * 64, l0 = blockIdx.y * 64;
    int c = threadIdx.x & 63, r4 = threadIdx.x >> 6;
#pragma unroll
    for (int it = 0; it < 16; ++it) {
        int r = it * 4 + r4;
        t[r][c] = p[(size_t)(d0 + r) * L_TOK + l0 + c];
    }
    __syncthreads();
#pragma unroll
    for (int it = 0; it < 16; ++it) {
        int r = it * 4 + r4;
        size_t idx = (size_t)(l0 + r) * DMODEL + d0 + c;
        q[idx] = f2bf(bf2f(x[idx]) + t[c][r]);
    }
}

// ---------------- weight prepack: f32 [K][N] -> bf16 hi/lo transposed [Npad][K] ----
__global__ __launch_bounds__(256) void prepack_kernel(const float* __restrict__ W,
                                                      u16* __restrict__ hi,
                                                      u16* __restrict__ lo,
                                                      int K, int N, int Npad) {
    int idx = blockIdx.x * 256 + threadIdx.x;
    if (idx >= Npad * K) return;
    int n = idx / K, k = idx - n * K;
    float w = (n < N) ? W[(size_t)k * N + n] : 0.f;
    u16 h = f2bf(w);
    float rem = w - bf2f(h);
    hi[idx] = h;
    lo[idx] = f2bf(rem);
}

// combined Wattn (cols 0..199) + Wbox (cols 200..231), pad to 256; bias fused
__global__ __launch_bounds__(256) void prepack_comb(const float* __restrict__ Wa,
                                                    const float* __restrict__ Wb,
                                                    const float* __restrict__ ba,
                                                    const float* __restrict__ bb,
                                                    u16* __restrict__ hi,
                                                    u16* __restrict__ lo,
                                                    float* __restrict__ bias) {
    int idx = blockIdx.x * 256 + threadIdx.x;
    if (idx >= 256 * 256) return;
    int n = idx >> 8, k = idx & 255;
    float w = (n < 200) ? Wa[(size_t)k * 200 + n] : (n < 232 ? Wb[(size_t)k * 32 + n - 200] : 0.f);
    u16 h = f2bf(w);
    hi[idx] = h;
    lo[idx] = f2bf(w - bf2f(h));
    if (k == 0) bias[n] = (n < 200) ? ba[n] : (n < 232 ? bb[n - 200] : 0.f);
}

// ---------------- MFMA GEMM: 2-phase dbuf + both-sides XOR swizzle (rule #21) ----
// C[M][ldC](bf16) = A[M][K](bf16) @ (Whi+Wlo)^T + bias, optional relu.
// Whi/Wlo are [Npad][K] (n-major). BN=64, BK=64, 4 waves (2x2). grid (Npad/64, M/BMv).
// LDS row r, 16B-slot s holds global (r, s ^ (r&7)): the global SOURCE address is
// pre-swizzled (gload_lds dest stays linear), the read applies the same XOR.
// -> ds_read_b128 goes 16-way conflicted -> 2-way (free, m136).
#define BN 64
#define BK 64

template<int BMv>
__global__ __launch_bounds__(256) void gemm_mfma(const u16* __restrict__ A,
                                                 const u16* __restrict__ Bhi,
                                                 const u16* __restrict__ Blo,
                                                 const float* __restrict__ bias,
                                                 u16* __restrict__ C,
                                                 int K, int Nact, int ldC, int relu) {
    constexpr int ASZ = BMv * BK;
    constexpr int BSZ = BN * BK;
    constexpr int ACH = BMv / 32;
    constexpr int NI  = BMv / 32;
    __shared__ __align__(16) u16 lds[2][ASZ + 2 * BSZ];  // BMv=128: 64 KB

    const int tid  = threadIdx.x;
    const int lane = tid & 63;
    const int wave = tid >> 6;
    const int wm = wave >> 1, wn = wave & 1;
    const int row = lane & 15, kch = lane >> 4;
    const int m0 = blockIdx.y * BMv;
    const int n0 = blockIdx.x * BN;

    // pre-swizzled global source: thread stages LDS slot (tid&7) of row (tid>>3);
    // fetch global slot (tid&7)^(srow&7). Chunk offsets are +32 rows -> (r&7) invariant.
    const int srow  = tid >> 3;
    const int sslot = (tid & 7) ^ (srow & 7);
    const u16* ga  = A   + (size_t)(m0 + srow) * K + sslot * 8;
    const u16* gbh = Bhi + (size_t)(n0 + srow) * K + sslot * 8;
    const u16* gbl = Blo + (size_t)(n0 + srow) * K + sslot * 8;

    f32x4 acc[NI][2] = {};
    const int nkt = K / BK;

    auto stage = [&](int kt, int buf) {
        u16* lb = &lds[buf][0];
        const int ko = kt * BK;
#pragma unroll
        for (int it = 0; it < ACH; ++it)
            gload16(ga + ko + (size_t)it * 32 * K, lb + tid * 8 + it * 2048);
#pragma unroll
        for (int it = 0; it < 2; ++it) {
            gload16(gbh + ko + (size_t)it * 32 * K, lb + ASZ + tid * 8 + it * 2048);
            gload16(gbl + ko + (size_t)it * 32 * K, lb + ASZ + BSZ + tid * 8 + it * 2048);
        }
    };

    stage(0, 0);
    __syncthreads();                      // tile 0 ready
    for (int t = 0; t < nkt; ++t) {
        const int cur = t & 1;
        if (t + 1 < nkt) stage(t + 1, cur ^ 1);   // prefetch next tile (other buffer)

        const u16* lb = &lds[cur][0];
#pragma unroll
        for (int kk = 0; kk < 2; ++kk) {
            const int ks = kk * 4 + kch;          // global 16B k-slot 0..7
            bf16x8 af[NI];
#pragma unroll
            for (int i = 0; i < NI; ++i) {
                const int r = wm * (BMv / 2) + i * 16 + row;
                af[i] = *(const bf16x8*)(lb + r * BK + ((ks ^ (r & 7)) * 8));
            }
#pragma unroll
            for (int j = 0; j < 2; ++j) {
                const int rb = wn * 32 + j * 16 + row;
                bf16x8 bh = *(const bf16x8*)(lb + ASZ + rb * BK + ((ks ^ (rb & 7)) * 8));
                bf16x8 bl = *(const bf16x8*)(lb + ASZ + BSZ + rb * BK + ((ks ^ (rb & 7)) * 8));
#pragma unroll
                for (int i = 0; i < NI; ++i) {
                    acc[i][j] = __builtin_amdgcn_mfma_f32_16x16x32_bf16(af[i], bh, acc[i][j], 0, 0, 0);
                    acc[i][j] = __builtin_amdgcn_mfma_f32_16x16x32_bf16(af[i], bl, acc[i][j], 0, 0, 0);
                }
            }
        }
        __syncthreads();   // drains prefetch (vmcnt 0) + joins reads; next buffer ready
    }

    // epilogue: C/D layout col = lane&15, row = (lane>>4)*4 + reg
    const int cm0 = m0 + wm * (BMv / 2) + (lane >> 4) * 4;
    const int cn0 = n0 + wn * 32 + (lane & 15);
#pragma unroll
    for (int j = 0; j < 2; ++j) {
        int cn = cn0 + j * 16;
        if (cn >= Nact) continue;
        float bv_ = bias[cn];
#pragma unroll
        for (int i = 0; i < NI; ++i) {
#pragma unroll
            for (int r = 0; r < 4; ++r) {
                float v = acc[i][j][r] + bv_;
                if (relu) v = fmaxf(v, 0.f);
                C[(size_t)(cm0 + i * 16 + r) * ldC + cn] = f2bf(v);
            }
        }
    }
}

// softmax over combined row layout: aw at row[n*25 .. n*25+24], row = awb + l*256
__global__ __launch_bounds__(256) void softmax_kernel(u16* __restrict__ awb, int total) {
    int t = blockIdx.x * blockDim.x + threadIdx.x;
    if (t >= total) return;
    int l = t >> 3, n = t & 7;
    u16* pp = awb + (size_t)l * 256 + n * 25;
    float v[25];
    float mx = -1e30f;
    for (int k = 0; k < 25; k++) { v[k] = bf2f(pp[k]); mx = fmaxf(mx, v[k]); }
    float s = 0.f;
    for (int k = 0; k < 25; k++) { v[k] = __expf(v[k] - mx); s += v[k]; }
    float inv = 1.f / s;
    for (int k = 0; k < 25; k++) pp[k] = f2bf(v[k] * inv);
}

// one thread = (pair, 8-wide hd chunk); branchless taps; combined awb layout
__global__ __launch_bounds__(256) void sample_kernel(const u16* __restrict__ val,
                                                     const u16* __restrict__ awb,
                                                     u16* __restrict__ out) {
    int tid = blockIdx.x * 256 + threadIdx.x;
    int ch = tid & 3;             // hd chunk (8 elems)
    int pair = tid >> 2;          // l*NH + n
    int n = pair & 7;
    int l = pair >> 3;
    int iy = l >> 7, ix = l & 127;
    float cx = (ix + 0.5f) * (1.f / 128.f);
    float cy = (iy + 0.5f) * (1.f / 128.f);
    const u16* rowp = awb + (size_t)l * 256;
    const u16* o = rowp + 200 + n * 4;
    float bx = cx + bf2f(o[0]) * (0.025f / 8.f);
    float by = cy + bf2f(o[1]) * (0.025f / 8.f);
    float bw = 0.025f + bf2f(o[2]) * (0.025f / 8.f);
    float bh = 0.025f + bf2f(o[3]) * (0.025f / 8.f);
    const u16* awp = rowp + n * 25;
    const u16* vbase = val + n * 32 + ch * 8;
    float acc[8] = {};
    for (int k = 0; k < 25; k++) {
        float gx = (float)(k % 5 - 2) * 0.25f;
        float gy = (float)(k / 5 - 2) * 0.25f;
        float xx = (bx + bw * gx) * 128.f - 0.5f;
        float yy = (by + bh * gy) * 128.f - 0.5f;
        float x0 = floorf(xx), y0 = floorf(yy);
        float a_ = bf2f(awp[k]);
#pragma unroll
        for (int dy = 0; dy < 2; dy++) {
#pragma unroll
            for (int dx = 0; dx < 2; dx++) {
                float xi = x0 + dx, yi = y0 + dy;
                float w_ = (1.f - fabsf(xx - xi)) * (1.f - fabsf(yy - yi)) * a_;
                bool valid = (xi >= 0.f) & (xi < 128.f) & (yi >= 0.f) & (yi < 128.f);
                w_ = valid ? w_ : 0.f;
                int ixi = min(max((int)xi, 0), 127);
                int iyi = min(max((int)yi, 0), 127);
                int idx = iyi * 128 + ixi;
                bf16x8 v = *(const bf16x8*)(vbase + (size_t)idx * 256);
#pragma unroll
                for (int e = 0; e < 8; e++)
                    acc[e] += w_ * bf2f((u16)v[e]);
            }
        }
    }
    bf16x8 ov;
#pragma unroll
    for (int e = 0; e < 8; e++) ov[e] = (short)f2bf(acc[e]);
    *(bf16x8*)(out + (size_t)l * 256 + n * 32 + ch * 8) = ov;
}

// ---------------- LayerNorm: one row per wave, fully in registers ----------------
__global__ __launch_bounds__(256) void ln_rows_bf16(const u16* __restrict__ xin,
                                                    const u16* __restrict__ delta,
                                                    const float* __restrict__ g,
                                                    const float* __restrict__ b,
                                                    u16* __restrict__ out) {
    int lane = threadIdx.x & 63;
    int row = blockIdx.x * 4 + (threadIdx.x >> 6);
    size_t base = (size_t)row * 256 + lane * 4;
    u16x4 xv = *(const u16x4*)(xin + base);
    u16x4 dv = *(const u16x4*)(delta + base);
    float v[4]; float s = 0.f, q = 0.f;
#pragma unroll
    for (int j = 0; j < 4; j++) {
        v[j] = bf2f(xv[j]) + bf2f(dv[j]);
        s += v[j]; q += v[j] * v[j];
    }
#pragma unroll
    for (int off = 1; off < 64; off <<= 1) {
        s += __shfl_xor(s, off, 64);
        q += __shfl_xor(q, off, 64);
    }
    float m = s * (1.f / 256.f);
    float var = q * (1.f / 256.f) - m * m;
    float r = rsqrtf(var + 1e-5f);
    f32x4 gv = *(const f32x4*)(g + lane * 4);
    f32x4 bv2 = *(const f32x4*)(b + lane * 4);
    u16x4 ov;
#pragma unroll
    for (int j = 0; j < 4; j++)
        ov[j] = f2bf((v[j] - m) * r * gv[j] + bv2[j]);
    *(u16x4*)(out + base) = ov;
}

// final LN writes FLOAT32 — d_out is the reference's output dtype (f32)
__global__ __launch_bounds__(256) void ln_rows_f32(const u16* __restrict__ xin,
                                                   const u16* __restrict__ delta,
                                                   const float* __restrict__ g,
                                                   const float* __restrict__ b,
                                                   float* __restrict__ out) {
    int lane = threadIdx.x & 63;
    int row = blockIdx.x * 4 + (threadIdx.x >> 6);
    size_t base = (size_t)row * 256 + lane * 4;
    u16x4 xv = *(const u16x4*)(xin + base);
    u16x4 dv = *(const u16x4*)(delta + base);
    float v[4]; float s = 0.f, q = 0.f;
#pragma unroll
    for (int j = 0; j < 4; j++) {
        v[j] = bf2f(xv[j]) + bf2f(dv[j]);
        s += v[j]; q += v[j] * v[j];
    }
#pragma unroll
    for (int off = 1; off < 64; off <<= 1) {
        s += __shfl_xor(s, off, 64);
        q += __shfl_xor(q, off, 64);
    }
    float m = s * (1.f / 256.f);
    float var = q * (1.f / 256.f) - m * m;
    float r = rsqrtf(var + 1e-5f);
    f32x4 gv = *(const f32x4*)(g + lane * 4);
    f32x4 bv2 = *(const f32x4*)(b + lane * 4);
    f32x4 ov;
#pragma unroll
    for (int j = 0; j < 4; j++)
        ov[j] = (v[j] - m) * r * gv[j] + bv2[j];
    *(f32x4*)(out + base) = ov;
}

extern "C" void kernel_launch(void* const* d_in, const int* in_sizes, int n_in,
                              void* d_out, int out_size, void* d_ws, size_t ws_size,
                              hipStream_t stream) {
    const size_t MiB = 1048576;
    float* outp = (float*)d_out;
    int fillg = (out_size + 255) / 256;

    // ---- environment sentinels ----
    const int exp_sizes[18] = {4194304, 4194304, 131072, 512, 16384, 64, 102400, 400,
                               131072, 512, 524288, 2048, 524288, 512, 512, 512, 512, 512};
    bool env_ok = (n_in == 18) && (ws_size >= 25 * MiB) && (out_size == 4194304);
    if (env_ok) for (int i = 0; i < 18; i++) env_ok = env_ok && (in_sizes[i] == exp_sizes[i]);
    if (!env_ok) {
        hipLaunchKernelGGL(fill_kernel, dim3(fillg), dim3(256), 0, stream, outp, out_size, 3000.f);
        return;
    }

    const float* srcp  = (const float*)d_in[0];
    const float* posp  = (const float*)d_in[1];
    const float* Wv    = (const float*)d_in[2];
    const float* bv    = (const float*)d_in[3];
    const float* Wbox  = (const float*)d_in[4];
    const float* bbox  = (const float*)d_in[5];
    const float* Wattn = (const float*)d_in[6];
    const float* battn = (const float*)d_in[7];
    const float* Wo    = (const float*)d_in[8];
    const float* bo    = (const float*)d_in[9];
    const float* W1    = (const float*)d_in[10];
    const float* b1    = (const float*)d_in[11];
    const float* W2    = (const float*)d_in[12];
    const float* b2    = (const float*)d_in[13];
    const float* ln1g  = (const float*)d_in[14];
    const float* ln1b  = (const float*)d_in[15];
    const float* ln2g  = (const float*)d_in[16];
    const float* ln2b  = (const float*)d_in[17];

    char* ws = (char*)d_ws;
    u16* x      = (u16*)(ws + 0);
    u16* q      = (u16*)(ws + 8 * MiB);
    u16* val    = (u16*)(ws + 8 * MiB);
    u16* hidden = (u16*)(ws + 8 * MiB);
    u16* awb    = (u16*)(ws + 16 * MiB);   // combined attn+box GEMM output [L][256]
    u16* tmp    = (u16*)(ws + 16 * MiB);
    u16* ffnout = (u16*)(ws + 16 * MiB);
    u16* attn   = (u16*)d_out;   // scratch in d_out bytes [0, 8 MiB)
    u16* wbuf   = (u16*)((char*)d_out + 8 * MiB);
    const size_t LSTR = 1474560;  // u16 elems per layer of packed weights

    const int ND = L_TOK * DMODEL;

    auto GM = [&](const u16* A, const u16* Whi, const u16* Wlo, const float* bias,
                  u16* C, int M, int K, int Npad, int Nact, int ldC, int relu, bool small) {
        if (small)
            hipLaunchKernelGGL((gemm_mfma<64>), dim3(Npad / 64, M / 64), dim3(256), 0, stream,
                               A, Whi, Wlo, bias, C, K, Nact, ldC, relu);
        else
            hipLaunchKernelGGL((gemm_mfma<128>), dim3(Npad / 64, M / 128), dim3(256), 0, stream,
                               A, Whi, Wlo, bias, C, K, Nact, ldC, relu);
    };
    auto PP = [&](const float* W, u16* hi, u16* lo, int K, int N, int Npad) {
        int tot = Npad * K;
        hipLaunchKernelGGL(prepack_kernel, dim3((tot + 255) / 256), dim3(256), 0, stream,
                           W, hi, lo, K, N, Npad);
    };

    // ---- prepack all weights (both layers) into d_out upper region ----
    // per-layer u16 offsets: comb_hi 0, comb_lo 65536, comb_bias(f32) 131072,
    //                        v 163840/229376, o 294912/360448, w1 425984/688128, w2 950272/1212416
    for (int i = 0; i < 2; i++) {
        u16* wb = wbuf + (size_t)i * LSTR;
        hipLaunchKernelGGL(prepack_comb, dim3(256), dim3(256), 0, stream,
                           Wattn + (size_t)i * 51200, Wbox + (size_t)i * 8192,
                           battn + (size_t)i * 200, bbox + (size_t)i * 32,
                           wb + 0, wb + 65536, (float*)(wb + 131072));
        PP(Wv + (size_t)i * 65536,  wb + 163840, wb + 229376,  256, 256, 256);
        PP(Wo + (size_t)i * 65536,  wb + 294912, wb + 360448,  256, 256, 256);
        PP(W1 + (size_t)i * 262144, wb + 425984, wb + 688128,  256, 1024, 1024);
        PP(W2 + (size_t)i * 262144, wb + 950272, wb + 1212416, 1024, 256, 256);
    }

    // x = src^T  (tiled, coalesced both sides)
    hipLaunchKernelGGL(xpose_tiled, dim3(4, 256), dim3(256), 0, stream, srcp, x);

    for (int i = 0; i < 2; i++) {
        u16* wb = wbuf + (size_t)i * LSTR;

        hipLaunchKernelGGL(addq_tiled, dim3(4, 256), dim3(256), 0, stream, x, posp, q);

        // combined attn+box GEMM -> awb [L][256]
        GM(q, wb + 0, wb + 65536, (const float*)(wb + 131072), awb,
           L_TOK, 256, 256, 256, 256, 0, false);
        hipLaunchKernelGGL(softmax_kernel, dim3((L_TOK * NHEAD + 255) / 256), dim3(256), 0,
                           stream, awb, L_TOK * NHEAD);

        GM(x, wb + 163840, wb + 229376, bv + (size_t)i * 256, val, L_TOK, 256, 256, 256, 256, 0, false);

        hipLaunchKernelGGL(sample_kernel, dim3(L_TOK * NHEAD * 4 / 256), dim3(256), 0, stream,
                           val, awb, attn);

        GM(attn, wb + 294912, wb + 360448, bo + (size_t)i * 256, tmp, L_TOK, 256, 256, 256, 256, 0, false);

        hipLaunchKernelGGL(ln_rows_bf16, dim3(L_TOK / 4), dim3(256), 0, stream,
                           x, tmp, ln1g + (size_t)i * 256, ln1b + (size_t)i * 256, x);

        for (int mc = 0; mc < 4; mc++) {
            const u16* xa = x + (size_t)mc * 4096 * 256;
            u16* ya = ffnout + (size_t)mc * 4096 * 256;
            GM(xa, wb + 425984, wb + 688128, b1 + (size_t)i * 1024, hidden, 4096, 256, 1024, 1024, 1024, 1, false);
            GM(hidden, wb + 950272, wb + 1212416, b2 + (size_t)i * 256, ya, 4096, 1024, 256, 256, 256, 0, true);
        }

        if (i == 0) {
            hipLaunchKernelGGL(ln_rows_bf16, dim3(L_TOK / 4), dim3(256), 0, stream,
                               x, ffnout, ln2g, ln2b, x);
        } else {
            // FINAL: float32 output
            hipLaunchKernelGGL(ln_rows_f32, dim3(L_TOK / 4), dim3(256), 0, stream,
                               x, ffnout, ln2g + 256, ln2b + 256, outp);
        }
    }
}